// Round 6
// baseline (858.431 us; speedup 1.0000x reference)
//
#include <hip/hip_runtime.h>
#include <math.h>

#define B_ 16
#define S_ 256
#define T_ 2048
#define D_ 512
#define H_ 8
#define L_ 6
#define FF_ 2048
#define NM_ 80
#define M_ 4096  // B_*S_

typedef float floatx4 __attribute__((ext_vector_type(4)));
typedef __bf16 bf16x8 __attribute__((ext_vector_type(8)));
typedef unsigned short u16x8 __attribute__((ext_vector_type(8)));

__device__ __forceinline__ float bf2f(unsigned u) {
    return __uint_as_float((u & 0xffffu) << 16);
}
__device__ __forceinline__ unsigned short f2bf(float f) {
    unsigned u = __float_as_uint(f);
    unsigned r = u + 0x7fffu + ((u >> 16) & 1u);
    return (unsigned short)(r >> 16);
}
__device__ __forceinline__ void gload_lds16(const void* g, void* l) {
    __builtin_amdgcn_global_load_lds(
        (const __attribute__((address_space(1))) void*)g,
        (__attribute__((address_space(3))) void*)l, 16, 0, 0);
}

// ---------------------------------------------------------------------------
// Fused weight prep: all transposes (f32 [K][N] -> bf16 [N][K]) + cbias + mel_c0.
// Write phase packs 2 bf16 along K per 4B store.
// ---------------------------------------------------------------------------
__device__ __forceinline__ void tr_body(
    const float* __restrict__ src, unsigned short* __restrict__ dst,
    int K, int N, int bx, int by, int bz, float (*tile)[33], int Ns /*pad guard*/)
{
    const int k0 = by * 32, n0 = bx * 32;
    src += (size_t)bz * K * Ns;
    dst += (size_t)bz * K * N;
    const int tid = threadIdx.x;
    const int tx = tid & 31, ty = tid >> 5;
#pragma unroll
    for (int i = 0; i < 32; i += 8) {
        int n = n0 + tx;
        tile[ty + i][tx] = (n < Ns) ? src[(size_t)(k0 + ty + i) * Ns + n] : 0.f;
    }
    __syncthreads();
    const int tx2 = tid & 15, ty2 = tid >> 4;   // 16 x 16
#pragma unroll
    for (int i = 0; i < 32; i += 16) {
        unsigned lo = f2bf(tile[2 * tx2][ty2 + i]);
        unsigned hi = f2bf(tile[2 * tx2 + 1][ty2 + i]);
        *(unsigned*)(dst + (size_t)(n0 + ty2 + i) * K + k0 + 2 * tx2) = lo | (hi << 16);
    }
}

__global__ __launch_bounds__(256) void prep_weights(
    const float* __restrict__ Wqkv, const float* __restrict__ Wo,
    const float* __restrict__ W1, const float* __restrict__ W2,
    const float* __restrict__ melW1, const float* __restrict__ melW2,
    const float* __restrict__ durW1, const float* __restrict__ melb1,
    const float* __restrict__ melb2, const float* __restrict__ durb1,
    unsigned short* __restrict__ Wqkv_t, unsigned short* __restrict__ Wo_t,
    unsigned short* __restrict__ W1_t, unsigned short* __restrict__ W2_t,
    unsigned short* __restrict__ wcomb, unsigned short* __restrict__ melW2_t,
    float* __restrict__ cbias, float* __restrict__ c0)
{
    __shared__ float tile[32][33];
    int bid = blockIdx.x;
    if (bid < 4608) {            // Wqkv: 48 x 16 x 6
        int z = bid / 768, r = bid % 768;
        tr_body(Wqkv, Wqkv_t, 512, 1536, r % 48, r / 48, z, tile, 1536);
        return;
    }
    bid -= 4608;
    if (bid < 1536) {            // Wo: 16 x 16 x 6
        int z = bid / 256, r = bid % 256;
        tr_body(Wo, Wo_t, 512, 512, r % 16, r / 16, z, tile, 512);
        return;
    }
    bid -= 1536;
    if (bid < 6144) {            // W1: 64 x 16 x 6
        int z = bid / 1024, r = bid % 1024;
        tr_body(W1, W1_t, 512, 2048, r % 64, r / 64, z, tile, 2048);
        return;
    }
    bid -= 6144;
    if (bid < 6144) {            // W2: 16 x 64 x 6
        int z = bid / 1024, r = bid % 1024;
        tr_body(W2, W2_t, 2048, 512, r % 16, r / 16, z, tile, 512);
        return;
    }
    bid -= 6144;
    if (bid < 1024) {            // melW1 -> wcomb rows [0,2048)
        tr_body(melW1, wcomb, 512, 2304, bid % 64, bid / 64, 0, tile, 2048);
        return;
    }
    bid -= 1024;
    if (bid < 256) {             // melW2 pad: 4 x 64 (dst N=128, src Ns=80)
        tr_body(melW2, melW2_t, 2048, 128, bid % 4, bid / 4, 0, tile, 80);
        return;
    }
    bid -= 256;
    if (bid < 128) {             // durW1 -> wcomb rows [2048,2304)
        tr_body(durW1, wcomb + (size_t)2048 * 512, 512, 256, bid % 8, bid / 8, 0, tile, 256);
        return;
    }
    bid -= 128;
    if (bid < 9) {               // cbias = [mel_b1 | dur_b1], 2304 floats
        int idx = bid * 256 + threadIdx.x;
        cbias[idx] = (idx < 2048) ? melb1[idx] : durb1[idx - 2048];
        return;
    }
    bid -= 9;
    {                            // mel_c0: 80 blocks
        float* red = (float*)tile;
        const int c = bid;
        const int tid = threadIdx.x;
        float p = 0.f;
        for (int f = tid; f < 2048; f += 256)
            p += fmaxf(melb1[f], 0.f) * melW2[(size_t)f * 80 + c];
#pragma unroll
        for (int off = 32; off >= 1; off >>= 1) p += __shfl_xor(p, off, 64);
        if ((tid & 63) == 0) red[tid >> 6] = p;
        __syncthreads();
        if (tid == 0) c0[c] = red[0] + red[1] + red[2] + red[3] + melb2[c];
    }
}

// ---------------------------------------------------------------------------
// Embedding + positional encoding -> bf16 x
// ---------------------------------------------------------------------------
__global__ __launch_bounds__(128) void embed_bf16(
    const int* __restrict__ ids, const float* __restrict__ emb,
    const float* __restrict__ pe, unsigned short* __restrict__ x)
{
    const int r = blockIdx.x;
    const int c = threadIdx.x * 4;
    const int id = ids[r];
    const int s = r & (S_ - 1);
    float4 e = *(const float4*)(emb + (size_t)id * D_ + c);
    float4 p = *(const float4*)(pe + (size_t)s * D_ + c);
    ushort4 o;
    o.x = f2bf(e.x + p.x); o.y = f2bf(e.y + p.y);
    o.z = f2bf(e.z + p.z); o.w = f2bf(e.w + p.w);
    *(ushort4*)(x + (size_t)r * D_ + c) = o;
}

// ---------------------------------------------------------------------------
// bf16 MFMA GEMM (measured-best structure): double-buffered LDS, two raw
// s_barrier per K-step with COUNTED vmcnt(NL) — next-stage loads stay in
// flight across both barriers.
// [R3 lesson: "one barrier + vmcnt(0)" drains the pipe every K-step: +60 us.]
// ---------------------------------------------------------------------------
template<int BM, int BN>
__global__ __launch_bounds__(256) void gemm2(
    const unsigned short* __restrict__ A, const unsigned short* __restrict__ Bt,
    const float* __restrict__ bias, unsigned short* __restrict__ Cb,
    float* __restrict__ Cpart, unsigned short* __restrict__ vtp,
    int N, int klen, int act, int lda)
{
    constexpr int NSUB_A = BM / 8;
    constexpr int NSUB_B = BN / 8;
    constexpr int NSUB = NSUB_A + NSUB_B;
    constexpr int NL = NSUB / 4;
    constexpr int BUFSZ = NSUB * 1024;
    constexpr int AOFF = NSUB_A * 1024;
    constexpr int WM = BM / 32, WN = BN / 32;
    __shared__ __attribute__((aligned(16))) char smem[2 * BUFSZ];

    const int tid = threadIdx.x;
    const int wave = tid >> 6, lane = tid & 63;
    const int lm = lane & 15, quad = lane >> 4;
    const int wm = wave >> 1, wn = wave & 1;
    const int m0 = blockIdx.y * BM;
    const int n0 = blockIdx.x * BN;
    const int Kfull = klen * gridDim.z;
    const int kb = blockIdx.z * klen;

    floatx4 acc[WM][WN];
#pragma unroll
    for (int i = 0; i < WM; i++)
#pragma unroll
        for (int j = 0; j < WN; j++) acc[i][j] = (floatx4){0.f, 0.f, 0.f, 0.f};

    const unsigned short* ga[NL];
    int loff[NL];
#pragma unroll
    for (int j = 0; j < NL; j++) {
        int sid = wave * NL + j;
        if (sid < NSUB_A) {
            int mi = sid >> 1, ki = sid & 1;
            ga[j] = A + (size_t)(m0 + mi * 16 + lm) * lda + kb + ki * 32 + quad * 8;
            loff[j] = sid * 1024;
        } else {
            int t = sid - NSUB_A;
            int ni = t >> 1, ki = t & 1;
            ga[j] = Bt + (size_t)(n0 + ni * 16 + lm) * Kfull + kb + ki * 32 + quad * 8;
            loff[j] = AOFF + t * 1024;
        }
    }

    // prologue: fill buffer 0
#pragma unroll
    for (int j = 0; j < NL; j++) gload_lds16(ga[j], smem + loff[j]);

    for (int kt = 0; kt < klen; kt += 64) {
        char* sc = smem + ((kt >> 6) & 1) * BUFSZ;
        if (kt + 64 < klen) {
            char* sn = smem + (((kt >> 6) + 1) & 1) * BUFSZ;
#pragma unroll
            for (int j = 0; j < NL; j++) gload_lds16(ga[j] + kt + 64, sn + loff[j]);
            __builtin_amdgcn_s_waitcnt(0x0F70 | NL);   // own current-buffer loads done
        } else {
            __builtin_amdgcn_s_waitcnt(0x0F70);        // drain
        }
        asm volatile("" ::: "memory");
        __builtin_amdgcn_s_barrier();
        asm volatile("" ::: "memory");

#pragma unroll
        for (int ki = 0; ki < 2; ki++) {
            bf16x8 af[WM], bfr[WN];
#pragma unroll
            for (int i = 0; i < WM; i++)
                af[i] = *(const bf16x8*)(sc + ((((wm * WM + i) * 2 + ki) << 10) + (lane << 4)));
#pragma unroll
            for (int j = 0; j < WN; j++)
                bfr[j] = *(const bf16x8*)(sc + AOFF + ((((wn * WN + j) * 2 + ki) << 10) + (lane << 4)));
#pragma unroll
            for (int i = 0; i < WM; i++)
#pragma unroll
                for (int j = 0; j < WN; j++)
                    acc[i][j] = __builtin_amdgcn_mfma_f32_16x16x32_bf16(
                        af[i], bfr[j], acc[i][j], 0, 0, 0);
        }
        asm volatile("" ::: "memory");
        __builtin_amdgcn_s_barrier();   // all waves done reading sc before refill
        asm volatile("" ::: "memory");
    }

    if constexpr (BM == 128 && BN == 128) {
        // fused V transpose: write bias-added tile transposed to vt
        if (vtp != nullptr && n0 >= 1024) {
            unsigned short* sT = (unsigned short*)smem;  // [128 d][136 s]
#pragma unroll
            for (int mi = 0; mi < WM; mi++) {
                const int rl = wm * 64 + mi * 16 + quad * 4;   // s-local
#pragma unroll
                for (int nj = 0; nj < WN; nj++) {
                    const int cl = wn * 64 + nj * 16 + lm;     // d-local
                    const float bv = bias[n0 + cl];
                    ushort4 t4;
                    t4.x = f2bf(acc[mi][nj][0] + bv);
                    t4.y = f2bf(acc[mi][nj][1] + bv);
                    t4.z = f2bf(acc[mi][nj][2] + bv);
                    t4.w = f2bf(acc[mi][nj][3] + bv);
                    *(ushort4*)(sT + cl * 136 + rl) = t4;
                }
            }
            __syncthreads();
            const int b = m0 >> 8;
            const int s0 = m0 & 255;
            const int h0 = (n0 - 1024) >> 6;   // 2 heads per block
#pragma unroll
            for (int i = 0; i < 8; i++) {
                int idx = i * 256 + tid;
                int d = idx >> 4, c = idx & 15;
                uint4 v = *(const uint4*)(sT + d * 136 + c * 8);
                int bh = b * 8 + h0 + (d >> 6);
                *(uint4*)(vtp + ((size_t)bh * 64 + (d & 63)) * 256 + s0 + c * 8) = v;
            }
            return;
        }
    }

    if (gridDim.z == 1) {
#pragma unroll
        for (int mi = 0; mi < WM; mi++) {
            const int rb = m0 + wm * (WM * 16) + mi * 16 + quad * 4;
#pragma unroll
            for (int nj = 0; nj < WN; nj++) {
                const int col = n0 + wn * (WN * 16) + nj * 16 + lm;
                const float bv = bias[col];
#pragma unroll
                for (int r = 0; r < 4; r++) {
                    float o = acc[mi][nj][r] + bv;
                    if (act) o = fmaxf(o, 0.f);
                    Cb[(size_t)(rb + r) * N + col] = f2bf(o);
                }
            }
        }
    } else {
        float* Cp = Cpart + (size_t)blockIdx.z * gridDim.y * BM * N;
#pragma unroll
        for (int mi = 0; mi < WM; mi++) {
            const int rb = m0 + wm * (WM * 16) + mi * 16 + quad * 4;
#pragma unroll
            for (int nj = 0; nj < WN; nj++) {
                const int col = n0 + wn * (WN * 16) + nj * 16 + lm;
#pragma unroll
                for (int r = 0; r < 4; r++)
                    Cp[(size_t)(rb + r) * N + col] = acc[mi][nj][r];
            }
        }
    }
}

// ---------------------------------------------------------------------------
// Fused attention v3: QBLK=64, grid (4, 128), 256 threads, 34 KB LDS ->
// 2 blocks/CU co-resident (was 1 at QBLK=128: every stall latency-exposed).
// K staged once per block, shared by 4 waves (4 stages/bh; extra L2 traffic
// ~2 us total at 35 TB/s, bought 2x occupancy).
// [R4 lesson: QBLK=16 single-wave re-read K/V 16x/bh = +45 us. Stay >= 64.]
// S=QK^T -> no-max softmax (post-LN scores bounded; mask underflows to 0)
// -> full P (64x256) via LDS stride 264 (2-way-free banks, 16B aligned)
// -> O=PV -> /l -> bf16.
// ---------------------------------------------------------------------------
__global__ __launch_bounds__(256) void attn_fused(
    const unsigned short* __restrict__ qkv, const unsigned short* __restrict__ vt,
    const int* __restrict__ lens, unsigned short* __restrict__ o)
{
    __shared__ __attribute__((aligned(16))) char smem[34816];
    const int tid = threadIdx.x;
    const int wave = tid >> 6, lane = tid & 63;
    const int lm = lane & 15, quad = lane >> 4;
    const int qt = blockIdx.x;
    const int bh = blockIdx.y;
    const int b = bh >> 3, h = bh & 7;
    const int len = lens[b];
    const unsigned short* Qb = qkv + ((size_t)b * 256 + qt * 64) * 1536 + h * 64;
    const unsigned short* Kb = qkv + (size_t)b * 256 * 1536 + 512 + h * 64;
    const unsigned short* Vt = vt + (size_t)bh * 64 * 256;

#pragma unroll
    for (int j = 0; j < 8; j++) {
        int sid = wave * 8 + j;
        int nf = sid >> 1, kf = sid & 1;
        gload_lds16(Kb + (size_t)(nf * 16 + lm) * 1536 + kf * 32 + quad * 8,
                    smem + sid * 1024);
    }
    // Q fragment: 16 rows per wave
    bf16x8 aq[2];
#pragma unroll
    for (int kf = 0; kf < 2; kf++)
        aq[kf] = *(const bf16x8*)(Qb + (size_t)(wave * 16 + lm) * 1536
                                  + kf * 32 + quad * 8);
    __syncthreads();

    floatx4 accS[16];
#pragma unroll
    for (int nf = 0; nf < 16; nf++) accS[nf] = (floatx4){0.f, 0.f, 0.f, 0.f};

#pragma unroll
    for (int nf = 0; nf < 16; nf++) {
        bf16x8 bk0 = *(const bf16x8*)(smem + (nf * 2 + 0) * 1024 + lane * 16);
        bf16x8 bk1 = *(const bf16x8*)(smem + (nf * 2 + 1) * 1024 + lane * 16);
        accS[nf] = __builtin_amdgcn_mfma_f32_16x16x32_bf16(aq[0], bk0, accS[nf], 0, 0, 0);
        accS[nf] = __builtin_amdgcn_mfma_f32_16x16x32_bf16(aq[1], bk1, accS[nf], 0, 0, 0);
    }

    float lrow[4];
    const float scale = 0.125f;
#pragma unroll
    for (int r = 0; r < 4; r++) {
        float sum = 0.f;
#pragma unroll
        for (int nf = 0; nf < 16; nf++) {
            float s = accS[nf][r] * scale + ((nf * 16 + lm >= len) ? -1e9f : 0.f);
            float e = __expf(s);
            accS[nf][r] = e;
            sum += e;
        }
#pragma unroll
        for (int off = 1; off < 16; off <<= 1) sum += __shfl_xor(sum, off, 64);
        lrow[r] = sum;
    }

    floatx4 accO[4];
#pragma unroll
    for (int nj = 0; nj < 4; nj++) accO[nj] = (floatx4){0.f, 0.f, 0.f, 0.f};

    // single barrier: all waves done reading K-smem before P overwrites it.
    __syncthreads();
    unsigned short* sP = (unsigned short*)smem;   // [64 rows][264] shorts
    const int rbase = wave * 16;
#pragma unroll
    for (int nf = 0; nf < 16; nf++) {
        const int row = rbase + quad * 4;
        const int col = nf * 16 + lm;
#pragma unroll
        for (int r = 0; r < 4; r++)
            sP[(row + r) * 264 + col] = f2bf(accS[nf][r]);
    }
#pragma unroll
    for (int ks = 0; ks < 8; ks++) {
        bf16x8 ap = *(const bf16x8*)(sP + (rbase + lm) * 264 + ks * 32 + quad * 8);
#pragma unroll
        for (int nj = 0; nj < 4; nj++) {
            bf16x8 bv = *(const bf16x8*)(Vt + (size_t)(nj * 16 + lm) * 256
                                         + ks * 32 + quad * 8);
            accO[nj] = __builtin_amdgcn_mfma_f32_16x16x32_bf16(ap, bv, accO[nj], 0, 0, 0);
        }
    }

    float inv[4];
#pragma unroll
    for (int r = 0; r < 4; r++) inv[r] = 1.f / lrow[r];
    const int grow = b * 256 + qt * 64 + rbase + quad * 4;
#pragma unroll
    for (int nj = 0; nj < 4; nj++) {
        const int gcol = h * 64 + nj * 16 + lm;
#pragma unroll
        for (int r = 0; r < 4; r++)
            o[(size_t)(grow + r) * 512 + gcol] = f2bf(accO[nj][r] * inv[r]);
    }
}

// ---------------------------------------------------------------------------
// x = LayerNorm(x + y_bf16), wave-per-row: no LDS, no barriers. 8 rows/block.
// ---------------------------------------------------------------------------
__global__ __launch_bounds__(512) void add_ln_bf16(
    unsigned short* __restrict__ x, const unsigned short* __restrict__ y,
    const float* __restrict__ s, const float* __restrict__ bb)
{
    const int wave = threadIdx.x >> 6, lane = threadIdx.x & 63;
    const int row = blockIdx.x * 8 + wave;
    const int c = lane * 8;
    u16x8 xv = *(const u16x8*)(x + (size_t)row * D_ + c);
    u16x8 yv = *(const u16x8*)(y + (size_t)row * D_ + c);
    float h[8];
    float sum = 0.f;
#pragma unroll
    for (int j = 0; j < 8; j++) {
        h[j] = bf2f(xv[j]) + bf2f(yv[j]);
        sum += h[j];
    }
#pragma unroll
    for (int off = 32; off >= 1; off >>= 1) sum += __shfl_xor(sum, off, 64);
    float mean = sum * (1.f / 512.f);

    float d[8], sq = 0.f;
#pragma unroll
    for (int j = 0; j < 8; j++) {
        d[j] = h[j] - mean;
        sq += d[j] * d[j];
    }
#pragma unroll
    for (int off = 32; off >= 1; off >>= 1) sq += __shfl_xor(sq, off, 64);
    float rs = rsqrtf(sq * (1.f / 512.f) + 1e-5f);

    float4 sv0 = *(const float4*)(s + c), sv1 = *(const float4*)(s + c + 4);
    float4 bv0 = *(const float4*)(bb + c), bv1 = *(const float4*)(bb + c + 4);
    u16x8 ov;
    ov[0] = f2bf(d[0] * rs * sv0.x + bv0.x);
    ov[1] = f2bf(d[1] * rs * sv0.y + bv0.y);
    ov[2] = f2bf(d[2] * rs * sv0.z + bv0.z);
    ov[3] = f2bf(d[3] * rs * sv0.w + bv0.w);
    ov[4] = f2bf(d[4] * rs * sv1.x + bv1.x);
    ov[5] = f2bf(d[5] * rs * sv1.y + bv1.y);
    ov[6] = f2bf(d[6] * rs * sv1.z + bv1.z);
    ov[7] = f2bf(d[7] * rs * sv1.w + bv1.w);
    *(u16x8*)(x + (size_t)row * D_ + c) = ov;
}

// ---------------------------------------------------------------------------
// x = LayerNorm(x + p0 + p1 + bias), wave-per-row; optional enc out (fp32)
// ---------------------------------------------------------------------------
__global__ __launch_bounds__(512) void add_ln_part(
    unsigned short* __restrict__ x, const float* __restrict__ p0,
    const float* __restrict__ p1, const float* __restrict__ bias,
    const float* __restrict__ s, const float* __restrict__ bb,
    float* __restrict__ enc_opt)
{
    const int wave = threadIdx.x >> 6, lane = threadIdx.x & 63;
    const int row = blockIdx.x * 8 + wave;
    const int c = lane * 8;
    u16x8 xv = *(const u16x8*)(x + (size_t)row * D_ + c);
    float4 a0 = *(const float4*)(p0 + (size_t)row * D_ + c);
    float4 a1 = *(const float4*)(p0 + (size_t)row * D_ + c + 4);
    float4 q0 = *(const float4*)(p1 + (size_t)row * D_ + c);
    float4 q1 = *(const float4*)(p1 + (size_t)row * D_ + c + 4);
    float4 bi0 = *(const float4*)(bias + c);
    float4 bi1 = *(const float4*)(bias + c + 4);
    float h[8];
    h[0] = bf2f(xv[0]) + a0.x + q0.x + bi0.x;
    h[1] = bf2f(xv[1]) + a0.y + q0.y + bi0.y;
    h[2] = bf2f(xv[2]) + a0.z + q0.z + bi0.z;
    h[3] = bf2f(xv[3]) + a0.w + q0.w + bi0.w;
    h[4] = bf2f(xv[4]) + a1.x + q1.x + bi1.x;
    h[5] = bf2f(xv[5]) + a1.y + q1.y + bi1.y;
    h[6] = bf2f(xv[6]) + a1.z + q1.z + bi1.z;
    h[7] = bf2f(xv[7]) + a1.w + q1.w + bi1.w;

    float sum = 0.f;
#pragma unroll
    for (int j = 0; j < 8; j++) sum += h[j];
#pragma unroll
    for (int off = 32; off >= 1; off >>= 1) sum += __shfl_xor(sum, off, 64);
    float mean = sum * (1.f / 512.f);

    float d[8], sq = 0.f;
#pragma unroll
    for (int j = 0; j < 8; j++) {
        d[j] = h[j] - mean;
        sq += d[j] * d[j];
    }
#pragma unroll
    for (int off = 32; off >= 1; off >>= 1) sq += __shfl_xor(sq, off, 64);
    float rs = rsqrtf(sq * (1.f / 512.f) + 1e-5f);

    float4 sv0 = *(const float4*)(s + c), sv1 = *(const float4*)(s + c + 4);
    float4 bv0 = *(const float4*)(bb + c), bv1 = *(const float4*)(bb + c + 4);
    float o[8];
    o[0] = d[0] * rs * sv0.x + bv0.x;
    o[1] = d[1] * rs * sv0.y + bv0.y;
    o[2] = d[2] * rs * sv0.z + bv0.z;
    o[3] = d[3] * rs * sv0.w + bv0.w;
    o[4] = d[4] * rs * sv1.x + bv1.x;
    o[5] = d[5] * rs * sv1.y + bv1.y;
    o[6] = d[6] * rs * sv1.z + bv1.z;
    o[7] = d[7] * rs * sv1.w + bv1.w;
    u16x8 ov;
#pragma unroll
    for (int j = 0; j < 8; j++) ov[j] = f2bf(o[j]);
    *(u16x8*)(x + (size_t)row * D_ + c) = ov;
    if (enc_opt) {
        float4 e0, e1;
        e0.x = o[0]; e0.y = o[1]; e0.z = o[2]; e0.w = o[3];
        e1.x = o[4]; e1.y = o[5]; e1.z = o[6]; e1.w = o[7];
        *(float4*)(enc_opt + (size_t)row * D_ + c) = e0;
        *(float4*)(enc_opt + (size_t)row * D_ + c + 4) = e1;
    }
}

// ---------------------------------------------------------------------------
// Head aux (merged): blocks [0,1024) = duration rows (hidden cols
// [2048,2304) of hcomb . w2 + b2 -> softplus -> round/clamp -> dint);
// blocks [1024,2304) = mel partial combine (melc = sum4(planes) + b2).
// ---------------------------------------------------------------------------
__global__ __launch_bounds__(256) void head_aux(
    const unsigned short* __restrict__ hcomb, const float* __restrict__ w2,
    const float* __restrict__ b2d, float* __restrict__ durout,
    int* __restrict__ dint,
    const float* __restrict__ mp, const float* __restrict__ b2m,
    float* __restrict__ melc)
{
    const int tid = threadIdx.x;
    int bid = blockIdx.x;
    if (bid < 1024) {
        const int w = tid >> 6, lane = tid & 63;
        const int r = bid * 4 + w;
        ushort4 hv = *(const ushort4*)(hcomb + (size_t)r * 2304 + 2048 + lane * 4);
        float4 wv = *(const float4*)(w2 + lane * 4);
        float p = bf2f(hv.x) * wv.x + bf2f(hv.y) * wv.y
                + bf2f(hv.z) * wv.z + bf2f(hv.w) * wv.w;
#pragma unroll
        for (int off = 32; off >= 1; off >>= 1) p += __shfl_xor(p, off, 64);
        if (lane == 0) {
            float v = p + b2d[0];
            float dur = (v > 20.f) ? v : log1pf(expf(v));
            durout[r] = dur;
            int d = (int)rintf(dur);
            if (d < 1) d = 1;
            dint[r] = d;
        }
        return;
    }
    bid -= 1024;
    const int idx = bid * 256 + tid;   // < 4096*80
    const int r = idx / 80, c = idx - r * 80;
    const size_t plane = (size_t)M_ * 128;
    const size_t base = (size_t)r * 128 + c;
    melc[idx] = mp[base] + mp[plane + base] + mp[2 * plane + base]
              + mp[3 * plane + base] + b2m[c];
}

// ---------------------------------------------------------------------------
// mel gather v4: per-batch cumsum computed in-block from dint (kills the
// separate dur_scan kernel; 256-int LDS scan is sub-us), LDS-staged rows,
// coalesced writes. grid (T/256, 2 col-halves, B). melc = [4096][80] fp32.
// ---------------------------------------------------------------------------
__global__ __launch_bounds__(256) void mel_gather2(
    const float* __restrict__ melc, const float* __restrict__ c0,
    const int* __restrict__ dint, float* __restrict__ mel_out)
{
    __shared__ float rows[256 * 40];
    __shared__ int sc[256];
    __shared__ float s0[40];
    const int tid = threadIdx.x;
    const int b = blockIdx.z;
    const int cc0 = blockIdx.y * 40;
    sc[tid] = dint[b * 256 + tid];
    if (tid < 40) s0[tid] = c0[cc0 + tid];
    for (int idx = tid; idx < 256 * 40; idx += 256) {
        int r = idx / 40, c = idx - r * 40;
        rows[idx] = melc[((size_t)b * 256 + r) * 80 + cc0 + c];
    }
    __syncthreads();
    // inclusive scan of sc[0..255]
    for (int off = 1; off < 256; off <<= 1) {
        int v = sc[tid];
        int add = (tid >= off) ? sc[tid - off] : 0;
        __syncthreads();
        sc[tid] = v + add;
        __syncthreads();
    }
    const int total = sc[255];
    const int t = blockIdx.x * 256 + tid;
    int lo = 0, hi = 256;
    while (lo < hi) {
        int mid = (lo + hi) >> 1;
        if (sc[mid] <= t) lo = mid + 1; else hi = mid;
    }
    int row = lo < 255 ? lo : 255;
    const bool valid = t < total;
    const float* src = valid ? &rows[row * 40] : s0;
    for (int cc = 0; cc < 40; cc++)
        mel_out[((size_t)b * 80 + cc0 + cc) * T_ + t] = src[cc];
}

// ---------------------------------------------------------------------------
extern "C" void kernel_launch(void* const* d_in, const int* in_sizes, int n_in,
                              void* d_out, int out_size, void* d_ws, size_t ws_size,
                              hipStream_t stream)
{
    const int*   text_ids     = (const int*)d_in[0];
    const int*   text_lengths = (const int*)d_in[1];
    const float* emb   = (const float*)d_in[3];
    const float* pe    = (const float*)d_in[4];
    const float* Wqkv  = (const float*)d_in[5];
    const float* bqkv  = (const float*)d_in[6];
    const float* Wo    = (const float*)d_in[7];
    const float* bo    = (const float*)d_in[8];
    const float* ln1_s = (const float*)d_in[9];
    const float* ln1_b = (const float*)d_in[10];
    const float* ln2_s = (const float*)d_in[11];
    const float* ln2_b = (const float*)d_in[12];
    const float* W1    = (const float*)d_in[13];
    const float* b1    = (const float*)d_in[14];
    const float* W2    = (const float*)d_in[15];
    const float* b2    = (const float*)d_in[16];
    const float* mel_W1 = (const float*)d_in[17];
    const float* mel_b1 = (const float*)d_in[18];
    const float* mel_W2 = (const float*)d_in[19];
    const float* mel_b2 = (const float*)d_in[20];
    const float* dur_W1 = (const float*)d_in[21];
    const float* dur_b1 = (const float*)d_in[22];
    const float* dur_W2 = (const float*)d_in[23];
    const float* dur_b2 = (const float*)d_in[24];

    float* out = (float*)d_out;
    float* mel_out = out;
    float* dur_out = out + (size_t)B_ * NM_ * T_;
    float* enc_out = dur_out + (size_t)B_ * S_;

    typedef unsigned short u16;
    char* w = (char*)d_ws;
    u16* Wqkv_t  = (u16*)w;                   w += (size_t)L_ * 1536 * 512 * 2;
    u16* Wo_t    = (u16*)w;                   w += (size_t)L_ * 512 * 512 * 2;
    u16* W1_t    = (u16*)w;                   w += (size_t)L_ * 2048 * 512 * 2;
    u16* W2_t    = (u16*)w;                   w += (size_t)L_ * 512 * 2048 * 2;
    u16* wcomb   = (u16*)w;                   w += (size_t)2304 * 512 * 2;   // [melW1|durW1]^T
    u16* melW2_t = (u16*)w;                   w += (size_t)128 * 2048 * 2;
    u16* x_bf    = (u16*)w;                   w += (size_t)M_ * 512 * 2;
    u16* qkv_bf  = (u16*)w;                   w += (size_t)M_ * 1536 * 2;  // contiguous with
    u16* ao_bf   = (u16*)w;                   w += (size_t)M_ * 512 * 2;   // ao: 16.78MB union
    u16* y_bf    = (u16*)w;                   w += (size_t)M_ * 512 * 2;
    char* big    = w;                         w += (size_t)18874368;       // ffh/hcomb (+vt tail)
    float* c0    = (float*)w;                 w += 512;
    int*   dint  = (int*)w;                   w += (size_t)M_ * 4;
    float* cbias = (float*)w;                 w += (size_t)2304 * 4;
    float* melc  = (float*)w;                 w += (size_t)M_ * 80 * 4;

    u16* ffh     = (u16*)big;                 // [4096][2048] bf16, layer phase
    u16* hcomb   = (u16*)big;                 // [4096][2304] bf16, head phase
    u16* vt      = (u16*)(big + 12582912);    // 4MB; alive only QKV->attn

    float* part2 = (float*)qkv_bf;            // [2][4096][512] for FF2
    float* mpart = (float*)(qkv_bf + (size_t)M_ * 512);  // [4][4096][128] for mel2

    // fused weight prep (all transposes + cbias + mel_c0): 19929 blocks
    prep_weights<<<19929, 256, 0, stream>>>(
        Wqkv, Wo, W1, W2, mel_W1, mel_W2, dur_W1, mel_b1, mel_b2, dur_b1,
        Wqkv_t, Wo_t, W1_t, W2_t, wcomb, melW2_t, cbias, c0);

    embed_bf16<<<M_, 128, 0, stream>>>(text_ids, emb, pe, x_bf);

    for (int l = 0; l < L_; l++) {
        // QKV with fused V-transpose epilogue (V cols -> vt, Q/K cols -> qkv_bf)
        gemm2<128, 128><<<dim3(12, 32), 256, 0, stream>>>(
            x_bf, Wqkv_t + (size_t)l * 1536 * 512, bqkv + (size_t)l * 1536,
            qkv_bf, nullptr, vt, 1536, 512, 0, 512);
        attn_fused<<<dim3(4, 128), 256, 0, stream>>>(qkv_bf, vt, text_lengths, ao_bf);
        gemm2<128, 64><<<dim3(8, 32), 256, 0, stream>>>(
            ao_bf, Wo_t + (size_t)l * 512 * 512, bo + (size_t)l * 512,
            y_bf, nullptr, nullptr, 512, 512, 0, 512);
        add_ln_bf16<<<M_ / 8, 512, 0, stream>>>(
            x_bf, y_bf, ln1_s + (size_t)l * D_, ln1_b + (size_t)l * D_);
        gemm2<128, 128><<<dim3(16, 32), 256, 0, stream>>>(
            x_bf, W1_t + (size_t)l * 2048 * 512, b1 + (size_t)l * 2048,
            ffh, nullptr, nullptr, 2048, 512, 1, 512);
        gemm2<128, 64><<<dim3(8, 32, 2), 256, 0, stream>>>(
            ffh, W2_t + (size_t)l * 512 * 2048, nullptr,
            nullptr, part2, nullptr, 512, 1024, 0, 2048);
        add_ln_part<<<M_ / 8, 512, 0, stream>>>(
            x_bf, part2, part2 + (size_t)M_ * 512, b2 + (size_t)l * 512,
            ln2_s + (size_t)l * D_, ln2_b + (size_t)l * D_,
            (l == L_ - 1) ? enc_out : nullptr);
    }

    // merged head hidden GEMM: hcomb = relu(enc.[melW1|durW1] + [mel_b1|dur_b1])
    gemm2<128, 128><<<dim3(18, 32), 256, 0, stream>>>(
        x_bf, wcomb, cbias, hcomb, nullptr, nullptr, 2304, 512, 1, 512);

    // mel2 (split-K=4 partials), then merged dur-rows + mel-combine
    gemm2<128, 64><<<dim3(2, 32, 4), 256, 0, stream>>>(
        hcomb, melW2_t, nullptr, nullptr, mpart, nullptr, 128, 512, 0, 2304);
    head_aux<<<2304, 256, 0, stream>>>(
        hcomb, dur_W2, dur_b2, dur_out, dint, mpart, mel_b2, melc);
    // gather computes the per-batch cumsum from dint in-block
    mel_gather2<<<dim3(T_ / 256, 2, B_), 256, 0, stream>>>(melc, c0, dint, mel_out);
}

// Round 7
// 831.876 us; speedup vs baseline: 1.0319x; 1.0319x over previous
//
#include <hip/hip_runtime.h>
#include <math.h>

#define B_ 16
#define S_ 256
#define T_ 2048
#define D_ 512
#define H_ 8
#define L_ 6
#define FF_ 2048
#define NM_ 80
#define M_ 4096  // B_*S_

typedef float floatx4 __attribute__((ext_vector_type(4)));
typedef __bf16 bf16x8 __attribute__((ext_vector_type(8)));
typedef unsigned short u16x8 __attribute__((ext_vector_type(8)));

__device__ __forceinline__ float bf2f(unsigned u) {
    return __uint_as_float((u & 0xffffu) << 16);
}
__device__ __forceinline__ unsigned short f2bf(float f) {
    unsigned u = __float_as_uint(f);
    unsigned r = u + 0x7fffu + ((u >> 16) & 1u);
    return (unsigned short)(r >> 16);
}
__device__ __forceinline__ void gload_lds16(const void* g, void* l) {
    __builtin_amdgcn_global_load_lds(
        (const __attribute__((address_space(1))) void*)g,
        (__attribute__((address_space(3))) void*)l, 16, 0, 0);
}

// ---------------------------------------------------------------------------
// Fused weight prep: all transposes (f32 [K][N] -> bf16 [N][K]) + cbias + mel_c0.
// Write phase packs 2 bf16 along K per 4B store.
// ---------------------------------------------------------------------------
__device__ __forceinline__ void tr_body(
    const float* __restrict__ src, unsigned short* __restrict__ dst,
    int K, int N, int bx, int by, int bz, float (*tile)[33], int Ns /*pad guard*/)
{
    const int k0 = by * 32, n0 = bx * 32;
    src += (size_t)bz * K * Ns;
    dst += (size_t)bz * K * N;
    const int tid = threadIdx.x;
    const int tx = tid & 31, ty = tid >> 5;
#pragma unroll
    for (int i = 0; i < 32; i += 8) {
        int n = n0 + tx;
        tile[ty + i][tx] = (n < Ns) ? src[(size_t)(k0 + ty + i) * Ns + n] : 0.f;
    }
    __syncthreads();
    const int tx2 = tid & 15, ty2 = tid >> 4;   // 16 x 16
#pragma unroll
    for (int i = 0; i < 32; i += 16) {
        unsigned lo = f2bf(tile[2 * tx2][ty2 + i]);
        unsigned hi = f2bf(tile[2 * tx2 + 1][ty2 + i]);
        *(unsigned*)(dst + (size_t)(n0 + ty2 + i) * K + k0 + 2 * tx2) = lo | (hi << 16);
    }
}

__global__ __launch_bounds__(256) void prep_weights(
    const float* __restrict__ Wqkv, const float* __restrict__ Wo,
    const float* __restrict__ W1, const float* __restrict__ W2,
    const float* __restrict__ melW1, const float* __restrict__ melW2,
    const float* __restrict__ durW1, const float* __restrict__ melb1,
    const float* __restrict__ melb2, const float* __restrict__ durb1,
    unsigned short* __restrict__ Wqkv_t, unsigned short* __restrict__ Wo_t,
    unsigned short* __restrict__ W1_t, unsigned short* __restrict__ W2_t,
    unsigned short* __restrict__ wcomb, unsigned short* __restrict__ melW2_t,
    float* __restrict__ cbias, float* __restrict__ c0)
{
    __shared__ float tile[32][33];
    int bid = blockIdx.x;
    if (bid < 4608) {            // Wqkv: 48 x 16 x 6
        int z = bid / 768, r = bid % 768;
        tr_body(Wqkv, Wqkv_t, 512, 1536, r % 48, r / 48, z, tile, 1536);
        return;
    }
    bid -= 4608;
    if (bid < 1536) {            // Wo: 16 x 16 x 6
        int z = bid / 256, r = bid % 256;
        tr_body(Wo, Wo_t, 512, 512, r % 16, r / 16, z, tile, 512);
        return;
    }
    bid -= 1536;
    if (bid < 6144) {            // W1: 64 x 16 x 6
        int z = bid / 1024, r = bid % 1024;
        tr_body(W1, W1_t, 512, 2048, r % 64, r / 64, z, tile, 2048);
        return;
    }
    bid -= 6144;
    if (bid < 6144) {            // W2: 16 x 64 x 6
        int z = bid / 1024, r = bid % 1024;
        tr_body(W2, W2_t, 2048, 512, r % 16, r / 16, z, tile, 512);
        return;
    }
    bid -= 6144;
    if (bid < 1024) {            // melW1 -> wcomb rows [0,2048)
        tr_body(melW1, wcomb, 512, 2304, bid % 64, bid / 64, 0, tile, 2048);
        return;
    }
    bid -= 1024;
    if (bid < 256) {             // melW2 pad: 4 x 64 (dst N=128, src Ns=80)
        tr_body(melW2, melW2_t, 2048, 128, bid % 4, bid / 4, 0, tile, 80);
        return;
    }
    bid -= 256;
    if (bid < 128) {             // durW1 -> wcomb rows [2048,2304)
        tr_body(durW1, wcomb + (size_t)2048 * 512, 512, 256, bid % 8, bid / 8, 0, tile, 256);
        return;
    }
    bid -= 128;
    if (bid < 9) {               // cbias = [mel_b1 | dur_b1], 2304 floats
        int idx = bid * 256 + threadIdx.x;
        cbias[idx] = (idx < 2048) ? melb1[idx] : durb1[idx - 2048];
        return;
    }
    bid -= 9;
    {                            // mel_c0: 80 blocks
        float* red = (float*)tile;
        const int c = bid;
        const int tid = threadIdx.x;
        float p = 0.f;
        for (int f = tid; f < 2048; f += 256)
            p += fmaxf(melb1[f], 0.f) * melW2[(size_t)f * 80 + c];
#pragma unroll
        for (int off = 32; off >= 1; off >>= 1) p += __shfl_xor(p, off, 64);
        if ((tid & 63) == 0) red[tid >> 6] = p;
        __syncthreads();
        if (tid == 0) c0[c] = red[0] + red[1] + red[2] + red[3] + melb2[c];
    }
}

// ---------------------------------------------------------------------------
// Embedding + positional encoding -> bf16 x
// ---------------------------------------------------------------------------
__global__ __launch_bounds__(128) void embed_bf16(
    const int* __restrict__ ids, const float* __restrict__ emb,
    const float* __restrict__ pe, unsigned short* __restrict__ x)
{
    const int r = blockIdx.x;
    const int c = threadIdx.x * 4;
    const int id = ids[r];
    const int s = r & (S_ - 1);
    float4 e = *(const float4*)(emb + (size_t)id * D_ + c);
    float4 p = *(const float4*)(pe + (size_t)s * D_ + c);
    ushort4 o;
    o.x = f2bf(e.x + p.x); o.y = f2bf(e.y + p.y);
    o.z = f2bf(e.z + p.z); o.w = f2bf(e.w + p.w);
    *(ushort4*)(x + (size_t)r * D_ + c) = o;
}

// ---------------------------------------------------------------------------
// bf16 MFMA GEMM (measured-best structure): double-buffered LDS, two raw
// s_barrier per K-step with COUNTED vmcnt(NL) — next-stage loads stay in
// flight across both barriers.
// [R3 lesson: "one barrier + vmcnt(0)" drains the pipe every K-step: +60 us.]
// ---------------------------------------------------------------------------
template<int BM, int BN>
__global__ __launch_bounds__(256) void gemm2(
    const unsigned short* __restrict__ A, const unsigned short* __restrict__ Bt,
    const float* __restrict__ bias, unsigned short* __restrict__ Cb,
    float* __restrict__ Cpart, unsigned short* __restrict__ vtp,
    int N, int klen, int act, int lda)
{
    constexpr int NSUB_A = BM / 8;
    constexpr int NSUB_B = BN / 8;
    constexpr int NSUB = NSUB_A + NSUB_B;
    constexpr int NL = NSUB / 4;
    constexpr int BUFSZ = NSUB * 1024;
    constexpr int AOFF = NSUB_A * 1024;
    constexpr int WM = BM / 32, WN = BN / 32;
    __shared__ __attribute__((aligned(16))) char smem[2 * BUFSZ];

    const int tid = threadIdx.x;
    const int wave = tid >> 6, lane = tid & 63;
    const int lm = lane & 15, quad = lane >> 4;
    const int wm = wave >> 1, wn = wave & 1;
    const int m0 = blockIdx.y * BM;
    const int n0 = blockIdx.x * BN;
    const int Kfull = klen * gridDim.z;
    const int kb = blockIdx.z * klen;

    floatx4 acc[WM][WN];
#pragma unroll
    for (int i = 0; i < WM; i++)
#pragma unroll
        for (int j = 0; j < WN; j++) acc[i][j] = (floatx4){0.f, 0.f, 0.f, 0.f};

    const unsigned short* ga[NL];
    int loff[NL];
#pragma unroll
    for (int j = 0; j < NL; j++) {
        int sid = wave * NL + j;
        if (sid < NSUB_A) {
            int mi = sid >> 1, ki = sid & 1;
            ga[j] = A + (size_t)(m0 + mi * 16 + lm) * lda + kb + ki * 32 + quad * 8;
            loff[j] = sid * 1024;
        } else {
            int t = sid - NSUB_A;
            int ni = t >> 1, ki = t & 1;
            ga[j] = Bt + (size_t)(n0 + ni * 16 + lm) * Kfull + kb + ki * 32 + quad * 8;
            loff[j] = AOFF + t * 1024;
        }
    }

    // prologue: fill buffer 0
#pragma unroll
    for (int j = 0; j < NL; j++) gload_lds16(ga[j], smem + loff[j]);

    for (int kt = 0; kt < klen; kt += 64) {
        char* sc = smem + ((kt >> 6) & 1) * BUFSZ;
        if (kt + 64 < klen) {
            char* sn = smem + (((kt >> 6) + 1) & 1) * BUFSZ;
#pragma unroll
            for (int j = 0; j < NL; j++) gload_lds16(ga[j] + kt + 64, sn + loff[j]);
            __builtin_amdgcn_s_waitcnt(0x0F70 | NL);   // own current-buffer loads done
        } else {
            __builtin_amdgcn_s_waitcnt(0x0F70);        // drain
        }
        asm volatile("" ::: "memory");
        __builtin_amdgcn_s_barrier();
        asm volatile("" ::: "memory");

#pragma unroll
        for (int ki = 0; ki < 2; ki++) {
            bf16x8 af[WM], bfr[WN];
#pragma unroll
            for (int i = 0; i < WM; i++)
                af[i] = *(const bf16x8*)(sc + ((((wm * WM + i) * 2 + ki) << 10) + (lane << 4)));
#pragma unroll
            for (int j = 0; j < WN; j++)
                bfr[j] = *(const bf16x8*)(sc + AOFF + ((((wn * WN + j) * 2 + ki) << 10) + (lane << 4)));
#pragma unroll
            for (int i = 0; i < WM; i++)
#pragma unroll
                for (int j = 0; j < WN; j++)
                    acc[i][j] = __builtin_amdgcn_mfma_f32_16x16x32_bf16(
                        af[i], bfr[j], acc[i][j], 0, 0, 0);
        }
        asm volatile("" ::: "memory");
        __builtin_amdgcn_s_barrier();   // all waves done reading sc before refill
        asm volatile("" ::: "memory");
    }

    if constexpr (BM == 128 && BN == 128) {
        // fused V transpose: write bias-added tile transposed to vt
        if (vtp != nullptr && n0 >= 1024) {
            unsigned short* sT = (unsigned short*)smem;  // [128 d][136 s]
#pragma unroll
            for (int mi = 0; mi < WM; mi++) {
                const int rl = wm * 64 + mi * 16 + quad * 4;   // s-local
#pragma unroll
                for (int nj = 0; nj < WN; nj++) {
                    const int cl = wn * 64 + nj * 16 + lm;     // d-local
                    const float bv = bias[n0 + cl];
                    ushort4 t4;
                    t4.x = f2bf(acc[mi][nj][0] + bv);
                    t4.y = f2bf(acc[mi][nj][1] + bv);
                    t4.z = f2bf(acc[mi][nj][2] + bv);
                    t4.w = f2bf(acc[mi][nj][3] + bv);
                    *(ushort4*)(sT + cl * 136 + rl) = t4;
                }
            }
            __syncthreads();
            const int b = m0 >> 8;
            const int s0 = m0 & 255;
            const int h0 = (n0 - 1024) >> 6;   // 2 heads per block
#pragma unroll
            for (int i = 0; i < 8; i++) {
                int idx = i * 256 + tid;
                int d = idx >> 4, c = idx & 15;
                uint4 v = *(const uint4*)(sT + d * 136 + c * 8);
                int bh = b * 8 + h0 + (d >> 6);
                *(uint4*)(vtp + ((size_t)bh * 64 + (d & 63)) * 256 + s0 + c * 8) = v;
            }
            return;
        }
    }

    if (gridDim.z == 1) {
#pragma unroll
        for (int mi = 0; mi < WM; mi++) {
            const int rb = m0 + wm * (WM * 16) + mi * 16 + quad * 4;
#pragma unroll
            for (int nj = 0; nj < WN; nj++) {
                const int col = n0 + wn * (WN * 16) + nj * 16 + lm;
                const float bv = bias[col];
#pragma unroll
                for (int r = 0; r < 4; r++) {
                    float o = acc[mi][nj][r] + bv;
                    if (act) o = fmaxf(o, 0.f);
                    Cb[(size_t)(rb + r) * N + col] = f2bf(o);
                }
            }
        }
    } else {
        float* Cp = Cpart + (size_t)blockIdx.z * gridDim.y * BM * N;
#pragma unroll
        for (int mi = 0; mi < WM; mi++) {
            const int rb = m0 + wm * (WM * 16) + mi * 16 + quad * 4;
#pragma unroll
            for (int nj = 0; nj < WN; nj++) {
                const int col = n0 + wn * (WN * 16) + nj * 16 + lm;
#pragma unroll
                for (int r = 0; r < 4; r++)
                    Cp[(size_t)(rb + r) * N + col] = acc[mi][nj][r];
            }
        }
    }
}

// ---------------------------------------------------------------------------
// Fused attention (QBLK=128 form, measured 836.9): per (q-tile 128, bh).
// K staged ONCE to LDS, shared by 4 waves. S=QK^T -> no-max softmax (post-LN
// scores bounded; mask underflows to 0) -> P via LDS (wave-private rows,
// single barrier) -> O=PV -> /l -> bf16.
// [R4 lesson: QBLK=16 re-reads K/V 16x/bh = +45 us.]
// [R5 lesson: QBLK=64 doubles K-staging per computed row = +25 us. Attn is
//  staged-bandwidth-bound, not latency-bound. QBLK=128 is final.]
// ---------------------------------------------------------------------------
__global__ __launch_bounds__(256) void attn_fused(
    const unsigned short* __restrict__ qkv, const unsigned short* __restrict__ vt,
    const int* __restrict__ lens, unsigned short* __restrict__ o)
{
    __shared__ __attribute__((aligned(16))) char smem[34816];
    const int tid = threadIdx.x;
    const int wave = tid >> 6, lane = tid & 63;
    const int lm = lane & 15, quad = lane >> 4;
    const int qt = blockIdx.x;
    const int bh = blockIdx.y;
    const int b = bh >> 3, h = bh & 7;
    const int len = lens[b];
    const unsigned short* Qb = qkv + ((size_t)b * 256 + qt * 128) * 1536 + h * 64;
    const unsigned short* Kb = qkv + (size_t)b * 256 * 1536 + 512 + h * 64;
    const unsigned short* Vt = vt + (size_t)bh * 64 * 256;

#pragma unroll
    for (int j = 0; j < 8; j++) {
        int sid = wave * 8 + j;
        int nf = sid >> 1, kf = sid & 1;
        gload_lds16(Kb + (size_t)(nf * 16 + lm) * 1536 + kf * 32 + quad * 8,
                    smem + sid * 1024);
    }
    bf16x8 aq[2][2];
#pragma unroll
    for (int mi = 0; mi < 2; mi++)
#pragma unroll
        for (int kf = 0; kf < 2; kf++)
            aq[mi][kf] = *(const bf16x8*)(Qb + (size_t)(wave * 32 + mi * 16 + lm) * 1536
                                          + kf * 32 + quad * 8);
    __syncthreads();

    floatx4 accS[2][16];
#pragma unroll
    for (int mi = 0; mi < 2; mi++)
#pragma unroll
        for (int nf = 0; nf < 16; nf++) accS[mi][nf] = (floatx4){0.f, 0.f, 0.f, 0.f};

#pragma unroll
    for (int nf = 0; nf < 16; nf++) {
        bf16x8 bk0 = *(const bf16x8*)(smem + (nf * 2 + 0) * 1024 + lane * 16);
        bf16x8 bk1 = *(const bf16x8*)(smem + (nf * 2 + 1) * 1024 + lane * 16);
        accS[0][nf] = __builtin_amdgcn_mfma_f32_16x16x32_bf16(aq[0][0], bk0, accS[0][nf], 0, 0, 0);
        accS[0][nf] = __builtin_amdgcn_mfma_f32_16x16x32_bf16(aq[0][1], bk1, accS[0][nf], 0, 0, 0);
        accS[1][nf] = __builtin_amdgcn_mfma_f32_16x16x32_bf16(aq[1][0], bk0, accS[1][nf], 0, 0, 0);
        accS[1][nf] = __builtin_amdgcn_mfma_f32_16x16x32_bf16(aq[1][1], bk1, accS[1][nf], 0, 0, 0);
    }

    float lrow[2][4];
    const float scale = 0.125f;
#pragma unroll
    for (int mi = 0; mi < 2; mi++)
#pragma unroll
        for (int r = 0; r < 4; r++) {
            float sum = 0.f;
#pragma unroll
            for (int nf = 0; nf < 16; nf++) {
                float s = accS[mi][nf][r] * scale + ((nf * 16 + lm >= len) ? -1e9f : 0.f);
                float e = __expf(s);
                accS[mi][nf][r] = e;
                sum += e;
            }
#pragma unroll
            for (int off = 1; off < 16; off <<= 1) sum += __shfl_xor(sum, off, 64);
            lrow[mi][r] = sum;
        }

    floatx4 accO[2][4];
#pragma unroll
    for (int mi = 0; mi < 2; mi++)
#pragma unroll
        for (int nj = 0; nj < 4; nj++) accO[mi][nj] = (floatx4){0.f, 0.f, 0.f, 0.f};

    // single barrier: all waves done reading K-smem before P overwrites it.
    __syncthreads();
    unsigned short* sP = (unsigned short*)smem;
    const int rbase = wave * 32;
#pragma unroll
    for (int half = 0; half < 2; half++) {
#pragma unroll
        for (int mi = 0; mi < 2; mi++)
#pragma unroll
            for (int nf2 = 0; nf2 < 8; nf2++) {
                int nf = half * 8 + nf2;
                int row = rbase + mi * 16 + quad * 4;
                int col = nf2 * 16 + lm;
#pragma unroll
                for (int r = 0; r < 4; r++)
                    sP[(row + r) * 136 + col] = f2bf(accS[mi][nf][r]);
            }
#pragma unroll
        for (int ks2 = 0; ks2 < 4; ks2++) {
            bf16x8 ap[2];
#pragma unroll
            for (int mi = 0; mi < 2; mi++)
                ap[mi] = *(const bf16x8*)(sP + (rbase + mi * 16 + lm) * 136
                                          + ks2 * 32 + quad * 8);
            int ks = half * 4 + ks2;
#pragma unroll
            for (int nj = 0; nj < 4; nj++) {
                bf16x8 bv = *(const bf16x8*)(Vt + (size_t)(nj * 16 + lm) * 256
                                             + ks * 32 + quad * 8);
                accO[0][nj] = __builtin_amdgcn_mfma_f32_16x16x32_bf16(ap[0], bv, accO[0][nj], 0, 0, 0);
                accO[1][nj] = __builtin_amdgcn_mfma_f32_16x16x32_bf16(ap[1], bv, accO[1][nj], 0, 0, 0);
            }
        }
    }

#pragma unroll
    for (int mi = 0; mi < 2; mi++) {
        float inv[4];
#pragma unroll
        for (int r = 0; r < 4; r++) inv[r] = 1.f / lrow[mi][r];
        const int grow = b * 256 + qt * 128 + rbase + mi * 16 + quad * 4;
#pragma unroll
        for (int nj = 0; nj < 4; nj++) {
            const int gcol = h * 64 + nj * 16 + lm;
#pragma unroll
            for (int r = 0; r < 4; r++)
                o[(size_t)(grow + r) * 512 + gcol] = f2bf(accO[mi][nj][r] * inv[r]);
        }
    }
}

// ---------------------------------------------------------------------------
// x = LayerNorm(x + y_bf16), wave-per-row: no LDS, no barriers. 8 rows/block.
// ---------------------------------------------------------------------------
__global__ __launch_bounds__(512) void add_ln_bf16(
    unsigned short* __restrict__ x, const unsigned short* __restrict__ y,
    const float* __restrict__ s, const float* __restrict__ bb)
{
    const int wave = threadIdx.x >> 6, lane = threadIdx.x & 63;
    const int row = blockIdx.x * 8 + wave;
    const int c = lane * 8;
    u16x8 xv = *(const u16x8*)(x + (size_t)row * D_ + c);
    u16x8 yv = *(const u16x8*)(y + (size_t)row * D_ + c);
    float h[8];
    float sum = 0.f;
#pragma unroll
    for (int j = 0; j < 8; j++) {
        h[j] = bf2f(xv[j]) + bf2f(yv[j]);
        sum += h[j];
    }
#pragma unroll
    for (int off = 32; off >= 1; off >>= 1) sum += __shfl_xor(sum, off, 64);
    float mean = sum * (1.f / 512.f);

    float d[8], sq = 0.f;
#pragma unroll
    for (int j = 0; j < 8; j++) {
        d[j] = h[j] - mean;
        sq += d[j] * d[j];
    }
#pragma unroll
    for (int off = 32; off >= 1; off >>= 1) sq += __shfl_xor(sq, off, 64);
    float rs = rsqrtf(sq * (1.f / 512.f) + 1e-5f);

    float4 sv0 = *(const float4*)(s + c), sv1 = *(const float4*)(s + c + 4);
    float4 bv0 = *(const float4*)(bb + c), bv1 = *(const float4*)(bb + c + 4);
    u16x8 ov;
    ov[0] = f2bf(d[0] * rs * sv0.x + bv0.x);
    ov[1] = f2bf(d[1] * rs * sv0.y + bv0.y);
    ov[2] = f2bf(d[2] * rs * sv0.z + bv0.z);
    ov[3] = f2bf(d[3] * rs * sv0.w + bv0.w);
    ov[4] = f2bf(d[4] * rs * sv1.x + bv1.x);
    ov[5] = f2bf(d[5] * rs * sv1.y + bv1.y);
    ov[6] = f2bf(d[6] * rs * sv1.z + bv1.z);
    ov[7] = f2bf(d[7] * rs * sv1.w + bv1.w);
    *(u16x8*)(x + (size_t)row * D_ + c) = ov;
}

// ---------------------------------------------------------------------------
// x = LayerNorm(x + p0 + p1 + bias), wave-per-row; optional enc out (fp32)
// ---------------------------------------------------------------------------
__global__ __launch_bounds__(512) void add_ln_part(
    unsigned short* __restrict__ x, const float* __restrict__ p0,
    const float* __restrict__ p1, const float* __restrict__ bias,
    const float* __restrict__ s, const float* __restrict__ bb,
    float* __restrict__ enc_opt)
{
    const int wave = threadIdx.x >> 6, lane = threadIdx.x & 63;
    const int row = blockIdx.x * 8 + wave;
    const int c = lane * 8;
    u16x8 xv = *(const u16x8*)(x + (size_t)row * D_ + c);
    float4 a0 = *(const float4*)(p0 + (size_t)row * D_ + c);
    float4 a1 = *(const float4*)(p0 + (size_t)row * D_ + c + 4);
    float4 q0 = *(const float4*)(p1 + (size_t)row * D_ + c);
    float4 q1 = *(const float4*)(p1 + (size_t)row * D_ + c + 4);
    float4 bi0 = *(const float4*)(bias + c);
    float4 bi1 = *(const float4*)(bias + c + 4);
    float h[8];
    h[0] = bf2f(xv[0]) + a0.x + q0.x + bi0.x;
    h[1] = bf2f(xv[1]) + a0.y + q0.y + bi0.y;
    h[2] = bf2f(xv[2]) + a0.z + q0.z + bi0.z;
    h[3] = bf2f(xv[3]) + a0.w + q0.w + bi0.w;
    h[4] = bf2f(xv[4]) + a1.x + q1.x + bi1.x;
    h[5] = bf2f(xv[5]) + a1.y + q1.y + bi1.y;
    h[6] = bf2f(xv[6]) + a1.z + q1.z + bi1.z;
    h[7] = bf2f(xv[7]) + a1.w + q1.w + bi1.w;

    float sum = 0.f;
#pragma unroll
    for (int j = 0; j < 8; j++) sum += h[j];
#pragma unroll
    for (int off = 32; off >= 1; off >>= 1) sum += __shfl_xor(sum, off, 64);
    float mean = sum * (1.f / 512.f);

    float d[8], sq = 0.f;
#pragma unroll
    for (int j = 0; j < 8; j++) {
        d[j] = h[j] - mean;
        sq += d[j] * d[j];
    }
#pragma unroll
    for (int off = 32; off >= 1; off >>= 1) sq += __shfl_xor(sq, off, 64);
    float rs = rsqrtf(sq * (1.f / 512.f) + 1e-5f);

    float4 sv0 = *(const float4*)(s + c), sv1 = *(const float4*)(s + c + 4);
    float4 bv0 = *(const float4*)(bb + c), bv1 = *(const float4*)(bb + c + 4);
    float o[8];
    o[0] = d[0] * rs * sv0.x + bv0.x;
    o[1] = d[1] * rs * sv0.y + bv0.y;
    o[2] = d[2] * rs * sv0.z + bv0.z;
    o[3] = d[3] * rs * sv0.w + bv0.w;
    o[4] = d[4] * rs * sv1.x + bv1.x;
    o[5] = d[5] * rs * sv1.y + bv1.y;
    o[6] = d[6] * rs * sv1.z + bv1.z;
    o[7] = d[7] * rs * sv1.w + bv1.w;
    u16x8 ov;
#pragma unroll
    for (int j = 0; j < 8; j++) ov[j] = f2bf(o[j]);
    *(u16x8*)(x + (size_t)row * D_ + c) = ov;
    if (enc_opt) {
        float4 e0, e1;
        e0.x = o[0]; e0.y = o[1]; e0.z = o[2]; e0.w = o[3];
        e1.x = o[4]; e1.y = o[5]; e1.z = o[6]; e1.w = o[7];
        *(float4*)(enc_opt + (size_t)row * D_ + c) = e0;
        *(float4*)(enc_opt + (size_t)row * D_ + c + 4) = e1;
    }
}

// ---------------------------------------------------------------------------
// Head aux (merged): blocks [0,1024) = duration rows (hidden cols
// [2048,2304) of hcomb . w2 + b2 -> softplus -> round/clamp -> dint);
// blocks [1024,2304) = mel partial combine (melc = sum4(planes) + b2).
// ---------------------------------------------------------------------------
__global__ __launch_bounds__(256) void head_aux(
    const unsigned short* __restrict__ hcomb, const float* __restrict__ w2,
    const float* __restrict__ b2d, float* __restrict__ durout,
    int* __restrict__ dint,
    const float* __restrict__ mp, const float* __restrict__ b2m,
    float* __restrict__ melc)
{
    const int tid = threadIdx.x;
    int bid = blockIdx.x;
    if (bid < 1024) {
        const int w = tid >> 6, lane = tid & 63;
        const int r = bid * 4 + w;
        ushort4 hv = *(const ushort4*)(hcomb + (size_t)r * 2304 + 2048 + lane * 4);
        float4 wv = *(const float4*)(w2 + lane * 4);
        float p = bf2f(hv.x) * wv.x + bf2f(hv.y) * wv.y
                + bf2f(hv.z) * wv.z + bf2f(hv.w) * wv.w;
#pragma unroll
        for (int off = 32; off >= 1; off >>= 1) p += __shfl_xor(p, off, 64);
        if (lane == 0) {
            float v = p + b2d[0];
            float dur = (v > 20.f) ? v : log1pf(expf(v));
            durout[r] = dur;
            int d = (int)rintf(dur);
            if (d < 1) d = 1;
            dint[r] = d;
        }
        return;
    }
    bid -= 1024;
    const int idx = bid * 256 + tid;   // < 4096*80
    const int r = idx / 80, c = idx - r * 80;
    const size_t plane = (size_t)M_ * 128;
    const size_t base = (size_t)r * 128 + c;
    melc[idx] = mp[base] + mp[plane + base] + mp[2 * plane + base]
              + mp[3 * plane + base] + b2m[c];
}

// ---------------------------------------------------------------------------
// mel gather v4: per-batch cumsum computed in-block from dint (removes the
// separate dur_scan launch; 256-int LDS scan is sub-us), LDS-staged rows,
// coalesced writes. grid (T/256, 2 col-halves, B). melc = [4096][80] fp32.
// ---------------------------------------------------------------------------
__global__ __launch_bounds__(256) void mel_gather2(
    const float* __restrict__ melc, const float* __restrict__ c0,
    const int* __restrict__ dint, float* __restrict__ mel_out)
{
    __shared__ float rows[256 * 40];
    __shared__ int sc[256];
    __shared__ float s0[40];
    const int tid = threadIdx.x;
    const int b = blockIdx.z;
    const int cc0 = blockIdx.y * 40;
    sc[tid] = dint[b * 256 + tid];
    if (tid < 40) s0[tid] = c0[cc0 + tid];
    for (int idx = tid; idx < 256 * 40; idx += 256) {
        int r = idx / 40, c = idx - r * 40;
        rows[idx] = melc[((size_t)b * 256 + r) * 80 + cc0 + c];
    }
    __syncthreads();
    // inclusive scan of sc[0..255]
    for (int off = 1; off < 256; off <<= 1) {
        int v = sc[tid];
        int add = (tid >= off) ? sc[tid - off] : 0;
        __syncthreads();
        sc[tid] = v + add;
        __syncthreads();
    }
    const int total = sc[255];
    const int t = blockIdx.x * 256 + tid;
    int lo = 0, hi = 256;
    while (lo < hi) {
        int mid = (lo + hi) >> 1;
        if (sc[mid] <= t) lo = mid + 1; else hi = mid;
    }
    int row = lo < 255 ? lo : 255;
    const bool valid = t < total;
    const float* src = valid ? &rows[row * 40] : s0;
    for (int cc = 0; cc < 40; cc++)
        mel_out[((size_t)b * 80 + cc0 + cc) * T_ + t] = src[cc];
}

// ---------------------------------------------------------------------------
extern "C" void kernel_launch(void* const* d_in, const int* in_sizes, int n_in,
                              void* d_out, int out_size, void* d_ws, size_t ws_size,
                              hipStream_t stream)
{
    const int*   text_ids     = (const int*)d_in[0];
    const int*   text_lengths = (const int*)d_in[1];
    const float* emb   = (const float*)d_in[3];
    const float* pe    = (const float*)d_in[4];
    const float* Wqkv  = (const float*)d_in[5];
    const float* bqkv  = (const float*)d_in[6];
    const float* Wo    = (const float*)d_in[7];
    const float* bo    = (const float*)d_in[8];
    const float* ln1_s = (const float*)d_in[9];
    const float* ln1_b = (const float*)d_in[10];
    const float* ln2_s = (const float*)d_in[11];
    const float* ln2_b = (const float*)d_in[12];
    const float* W1    = (const float*)d_in[13];
    const float* b1    = (const float*)d_in[14];
    const float* W2    = (const float*)d_in[15];
    const float* b2    = (const float*)d_in[16];
    const float* mel_W1 = (const float*)d_in[17];
    const float* mel_b1 = (const float*)d_in[18];
    const float* mel_W2 = (const float*)d_in[19];
    const float* mel_b2 = (const float*)d_in[20];
    const float* dur_W1 = (const float*)d_in[21];
    const float* dur_b1 = (const float*)d_in[22];
    const float* dur_W2 = (const float*)d_in[23];
    const float* dur_b2 = (const float*)d_in[24];

    float* out = (float*)d_out;
    float* mel_out = out;
    float* dur_out = out + (size_t)B_ * NM_ * T_;
    float* enc_out = dur_out + (size_t)B_ * S_;

    typedef unsigned short u16;
    char* w = (char*)d_ws;
    u16* Wqkv_t  = (u16*)w;                   w += (size_t)L_ * 1536 * 512 * 2;
    u16* Wo_t    = (u16*)w;                   w += (size_t)L_ * 512 * 512 * 2;
    u16* W1_t    = (u16*)w;                   w += (size_t)L_ * 2048 * 512 * 2;
    u16* W2_t    = (u16*)w;                   w += (size_t)L_ * 512 * 2048 * 2;
    u16* wcomb   = (u16*)w;                   w += (size_t)2304 * 512 * 2;   // [melW1|durW1]^T
    u16* melW2_t = (u16*)w;                   w += (size_t)128 * 2048 * 2;
    u16* x_bf    = (u16*)w;                   w += (size_t)M_ * 512 * 2;
    u16* qkv_bf  = (u16*)w;                   w += (size_t)M_ * 1536 * 2;  // contiguous with
    u16* ao_bf   = (u16*)w;                   w += (size_t)M_ * 512 * 2;   // ao: 16.78MB union
    u16* y_bf    = (u16*)w;                   w += (size_t)M_ * 512 * 2;
    char* big    = w;                         w += (size_t)18874368;       // ffh/hcomb (+vt tail)
    float* c0    = (float*)w;                 w += 512;
    int*   dint  = (int*)w;                   w += (size_t)M_ * 4;
    float* cbias = (float*)w;                 w += (size_t)2304 * 4;
    float* melc  = (float*)w;                 w += (size_t)M_ * 80 * 4;

    u16* ffh     = (u16*)big;                 // [4096][2048] bf16, layer phase
    u16* hcomb   = (u16*)big;                 // [4096][2304] bf16, head phase
    u16* vt      = (u16*)(big + 12582912);    // 4MB; alive only QKV->attn

    float* part2 = (float*)qkv_bf;            // [2][4096][512] for FF2
    float* mpart = (float*)(qkv_bf + (size_t)M_ * 512);  // [4][4096][128] for mel2

    // fused weight prep (all transposes + cbias + mel_c0): 19929 blocks
    prep_weights<<<19929, 256, 0, stream>>>(
        Wqkv, Wo, W1, W2, mel_W1, mel_W2, dur_W1, mel_b1, mel_b2, dur_b1,
        Wqkv_t, Wo_t, W1_t, W2_t, wcomb, melW2_t, cbias, c0);

    embed_bf16<<<M_, 128, 0, stream>>>(text_ids, emb, pe, x_bf);

    for (int l = 0; l < L_; l++) {
        // QKV with fused V-transpose epilogue (V cols -> vt, Q/K cols -> qkv_bf)
        gemm2<128, 128><<<dim3(12, 32), 256, 0, stream>>>(
            x_bf, Wqkv_t + (size_t)l * 1536 * 512, bqkv + (size_t)l * 1536,
            qkv_bf, nullptr, vt, 1536, 512, 0, 512);
        attn_fused<<<dim3(2, 128), 256, 0, stream>>>(qkv_bf, vt, text_lengths, ao_bf);
        gemm2<128, 64><<<dim3(8, 32), 256, 0, stream>>>(
            ao_bf, Wo_t + (size_t)l * 512 * 512, bo + (size_t)l * 512,
            y_bf, nullptr, nullptr, 512, 512, 0, 512);
        add_ln_bf16<<<M_ / 8, 512, 0, stream>>>(
            x_bf, y_bf, ln1_s + (size_t)l * D_, ln1_b + (size_t)l * D_);
        gemm2<128, 128><<<dim3(16, 32), 256, 0, stream>>>(
            x_bf, W1_t + (size_t)l * 2048 * 512, b1 + (size_t)l * 2048,
            ffh, nullptr, nullptr, 2048, 512, 1, 512);
        gemm2<128, 64><<<dim3(8, 32, 2), 256, 0, stream>>>(
            ffh, W2_t + (size_t)l * 512 * 2048, nullptr,
            nullptr, part2, nullptr, 512, 1024, 0, 2048);
        add_ln_part<<<M_ / 8, 512, 0, stream>>>(
            x_bf, part2, part2 + (size_t)M_ * 512, b2 + (size_t)l * 512,
            ln2_s + (size_t)l * D_, ln2_b + (size_t)l * D_,
            (l == L_ - 1) ? enc_out : nullptr);
    }

    // merged head hidden GEMM: hcomb = relu(enc.[melW1|durW1] + [mel_b1|dur_b1])
    gemm2<128, 128><<<dim3(18, 32), 256, 0, stream>>>(
        x_bf, wcomb, cbias, hcomb, nullptr, nullptr, 2304, 512, 1, 512);

    // mel2 (split-K=4 partials), then merged dur-rows + mel-combine
    gemm2<128, 64><<<dim3(2, 32, 4), 256, 0, stream>>>(
        hcomb, melW2_t, nullptr, nullptr, mpart, nullptr, 128, 512, 0, 2304);
    head_aux<<<2304, 256, 0, stream>>>(
        hcomb, dur_W2, dur_b2, dur_out, dint, mpart, mel_b2, melc);
    // gather computes the per-batch cumsum from dint in-block
    mel_gather2<<<dim3(T_ / 256, 2, B_), 256, 0, stream>>>(melc, c0, dint, mel_out);
}

// Round 9
// 829.019 us; speedup vs baseline: 1.0355x; 1.0034x over previous
//
#include <hip/hip_runtime.h>
#include <math.h>

#define B_ 16
#define S_ 256
#define T_ 2048
#define D_ 512
#define H_ 8
#define L_ 6
#define FF_ 2048
#define NM_ 80
#define M_ 4096  // B_*S_

typedef float floatx4 __attribute__((ext_vector_type(4)));
typedef __bf16 bf16x8 __attribute__((ext_vector_type(8)));
typedef unsigned short u16x8 __attribute__((ext_vector_type(8)));

__device__ __forceinline__ float bf2f(unsigned u) {
    return __uint_as_float((u & 0xffffu) << 16);
}
__device__ __forceinline__ unsigned short f2bf(float f) {
    unsigned u = __float_as_uint(f);
    unsigned r = u + 0x7fffu + ((u >> 16) & 1u);
    return (unsigned short)(r >> 16);
}
__device__ __forceinline__ void gload_lds16(const void* g, void* l) {
    __builtin_amdgcn_global_load_lds(
        (const __attribute__((address_space(1))) void*)g,
        (__attribute__((address_space(3))) void*)l, 16, 0, 0);
}

// ---------------------------------------------------------------------------
// Fused weight prep: all transposes (f32 [K][N] -> bf16 [N][K]) + cbias +
// mel_c0 + embedding (merged: independent work, fills prep's tail).
// ---------------------------------------------------------------------------
__device__ __forceinline__ void tr_body(
    const float* __restrict__ src, unsigned short* __restrict__ dst,
    int K, int N, int bx, int by, int bz, float (*tile)[33], int Ns /*pad guard*/)
{
    const int k0 = by * 32, n0 = bx * 32;
    src += (size_t)bz * K * Ns;
    dst += (size_t)bz * K * N;
    const int tid = threadIdx.x;
    const int tx = tid & 31, ty = tid >> 5;
#pragma unroll
    for (int i = 0; i < 32; i += 8) {
        int n = n0 + tx;
        tile[ty + i][tx] = (n < Ns) ? src[(size_t)(k0 + ty + i) * Ns + n] : 0.f;
    }
    __syncthreads();
    const int tx2 = tid & 15, ty2 = tid >> 4;   // 16 x 16
#pragma unroll
    for (int i = 0; i < 32; i += 16) {
        unsigned lo = f2bf(tile[2 * tx2][ty2 + i]);
        unsigned hi = f2bf(tile[2 * tx2 + 1][ty2 + i]);
        *(unsigned*)(dst + (size_t)(n0 + ty2 + i) * K + k0 + 2 * tx2) = lo | (hi << 16);
    }
}

__global__ __launch_bounds__(256) void prep_weights(
    const float* __restrict__ Wqkv, const float* __restrict__ Wo,
    const float* __restrict__ W1, const float* __restrict__ W2,
    const float* __restrict__ melW1, const float* __restrict__ melW2,
    const float* __restrict__ durW1, const float* __restrict__ melb1,
    const float* __restrict__ melb2, const float* __restrict__ durb1,
    const int* __restrict__ ids, const float* __restrict__ emb,
    const float* __restrict__ pe,
    unsigned short* __restrict__ Wqkv_t, unsigned short* __restrict__ Wo_t,
    unsigned short* __restrict__ W1_t, unsigned short* __restrict__ W2_t,
    unsigned short* __restrict__ wcomb, unsigned short* __restrict__ melW2_t,
    float* __restrict__ cbias, float* __restrict__ c0,
    unsigned short* __restrict__ x)
{
    __shared__ float tile[32][33];
    int bid = blockIdx.x;
    if (bid < 4608) {            // Wqkv: 48 x 16 x 6
        int z = bid / 768, r = bid % 768;
        tr_body(Wqkv, Wqkv_t, 512, 1536, r % 48, r / 48, z, tile, 1536);
        return;
    }
    bid -= 4608;
    if (bid < 1536) {            // Wo: 16 x 16 x 6
        int z = bid / 256, r = bid % 256;
        tr_body(Wo, Wo_t, 512, 512, r % 16, r / 16, z, tile, 512);
        return;
    }
    bid -= 1536;
    if (bid < 6144) {            // W1: 64 x 16 x 6
        int z = bid / 1024, r = bid % 1024;
        tr_body(W1, W1_t, 512, 2048, r % 64, r / 64, z, tile, 2048);
        return;
    }
    bid -= 6144;
    if (bid < 6144) {            // W2: 16 x 64 x 6
        int z = bid / 1024, r = bid % 1024;
        tr_body(W2, W2_t, 2048, 512, r % 16, r / 16, z, tile, 512);
        return;
    }
    bid -= 6144;
    if (bid < 1024) {            // melW1 -> wcomb rows [0,2048)
        tr_body(melW1, wcomb, 512, 2304, bid % 64, bid / 64, 0, tile, 2048);
        return;
    }
    bid -= 1024;
    if (bid < 256) {             // melW2 pad: 4 x 64 (dst N=128, src Ns=80)
        tr_body(melW2, melW2_t, 2048, 128, bid % 4, bid / 4, 0, tile, 80);
        return;
    }
    bid -= 256;
    if (bid < 128) {             // durW1 -> wcomb rows [2048,2304)
        tr_body(durW1, wcomb + (size_t)2048 * 512, 512, 256, bid % 8, bid / 8, 0, tile, 256);
        return;
    }
    bid -= 128;
    if (bid < 9) {               // cbias = [mel_b1 | dur_b1], 2304 floats
        int idx = bid * 256 + threadIdx.x;
        cbias[idx] = (idx < 2048) ? melb1[idx] : durb1[idx - 2048];
        return;
    }
    bid -= 9;
    if (bid < 80) {              // mel_c0: 80 blocks
        float* red = (float*)tile;
        const int c = bid;
        const int tid = threadIdx.x;
        float p = 0.f;
        for (int f = tid; f < 2048; f += 256)
            p += fmaxf(melb1[f], 0.f) * melW2[(size_t)f * 80 + c];
#pragma unroll
        for (int off = 32; off >= 1; off >>= 1) p += __shfl_xor(p, off, 64);
        if ((tid & 63) == 0) red[tid >> 6] = p;
        __syncthreads();
        if (tid == 0) c0[c] = red[0] + red[1] + red[2] + red[3] + melb2[c];
        return;
    }
    bid -= 80;
    {                            // embedding + PE: 2048 blocks, 2 rows each
        const int half = threadIdx.x >> 7;
        const int t = threadIdx.x & 127;
        const int r = bid * 2 + half;
        const int c = t * 4;
        const int id = ids[r];
        const int s = r & (S_ - 1);
        float4 e = *(const float4*)(emb + (size_t)id * D_ + c);
        float4 p = *(const float4*)(pe + (size_t)s * D_ + c);
        ushort4 o;
        o.x = f2bf(e.x + p.x); o.y = f2bf(e.y + p.y);
        o.z = f2bf(e.z + p.z); o.w = f2bf(e.w + p.w);
        *(ushort4*)(x + (size_t)r * D_ + c) = o;
    }
}

// ---------------------------------------------------------------------------
// bf16 MFMA GEMM (measured-best K-loop): double-buffered LDS, two raw
// s_barrier per K-step with COUNTED vmcnt(NL) — next-stage loads stay in
// flight across both barriers.
// [R3 lesson: "one barrier + vmcnt(0)" drains the pipe every K-step: +60 us.]
// R7: bf16 C-write staged through LDS -> uint4 stores (was 64 scalar
// 2B stores/thread; now 8x fewer store instrs, full-width bursts).
// ---------------------------------------------------------------------------
template<int BM, int BN>
__global__ __launch_bounds__(256) void gemm2(
    const unsigned short* __restrict__ A, const unsigned short* __restrict__ Bt,
    const float* __restrict__ bias, unsigned short* __restrict__ Cb,
    float* __restrict__ Cpart, unsigned short* __restrict__ vtp,
    int N, int klen, int act, int lda)
{
    constexpr int NSUB_A = BM / 8;
    constexpr int NSUB_B = BN / 8;
    constexpr int NSUB = NSUB_A + NSUB_B;
    constexpr int NL = NSUB / 4;
    constexpr int BUFSZ = NSUB * 1024;
    constexpr int AOFF = NSUB_A * 1024;
    constexpr int WM = BM / 32, WN = BN / 32;
    __shared__ __attribute__((aligned(16))) char smem[2 * BUFSZ];

    const int tid = threadIdx.x;
    const int wave = tid >> 6, lane = tid & 63;
    const int lm = lane & 15, quad = lane >> 4;
    const int wm = wave >> 1, wn = wave & 1;
    const int m0 = blockIdx.y * BM;
    const int n0 = blockIdx.x * BN;
    const int Kfull = klen * gridDim.z;
    const int kb = blockIdx.z * klen;

    floatx4 acc[WM][WN];
#pragma unroll
    for (int i = 0; i < WM; i++)
#pragma unroll
        for (int j = 0; j < WN; j++) acc[i][j] = (floatx4){0.f, 0.f, 0.f, 0.f};

    const unsigned short* ga[NL];
    int loff[NL];
#pragma unroll
    for (int j = 0; j < NL; j++) {
        int sid = wave * NL + j;
        if (sid < NSUB_A) {
            int mi = sid >> 1, ki = sid & 1;
            ga[j] = A + (size_t)(m0 + mi * 16 + lm) * lda + kb + ki * 32 + quad * 8;
            loff[j] = sid * 1024;
        } else {
            int t = sid - NSUB_A;
            int ni = t >> 1, ki = t & 1;
            ga[j] = Bt + (size_t)(n0 + ni * 16 + lm) * Kfull + kb + ki * 32 + quad * 8;
            loff[j] = AOFF + t * 1024;
        }
    }

    // prologue: fill buffer 0
#pragma unroll
    for (int j = 0; j < NL; j++) gload_lds16(ga[j], smem + loff[j]);

    for (int kt = 0; kt < klen; kt += 64) {
        char* sc = smem + ((kt >> 6) & 1) * BUFSZ;
        if (kt + 64 < klen) {
            char* sn = smem + (((kt >> 6) + 1) & 1) * BUFSZ;
#pragma unroll
            for (int j = 0; j < NL; j++) gload_lds16(ga[j] + kt + 64, sn + loff[j]);
            __builtin_amdgcn_s_waitcnt(0x0F70 | NL);   // own current-buffer loads done
        } else {
            __builtin_amdgcn_s_waitcnt(0x0F70);        // drain
        }
        asm volatile("" ::: "memory");
        __builtin_amdgcn_s_barrier();
        asm volatile("" ::: "memory");

#pragma unroll
        for (int ki = 0; ki < 2; ki++) {
            bf16x8 af[WM], bfr[WN];
#pragma unroll
            for (int i = 0; i < WM; i++)
                af[i] = *(const bf16x8*)(sc + ((((wm * WM + i) * 2 + ki) << 10) + (lane << 4)));
#pragma unroll
            for (int j = 0; j < WN; j++)
                bfr[j] = *(const bf16x8*)(sc + AOFF + ((((wn * WN + j) * 2 + ki) << 10) + (lane << 4)));
#pragma unroll
            for (int i = 0; i < WM; i++)
#pragma unroll
                for (int j = 0; j < WN; j++)
                    acc[i][j] = __builtin_amdgcn_mfma_f32_16x16x32_bf16(
                        af[i], bfr[j], acc[i][j], 0, 0, 0);
        }
        asm volatile("" ::: "memory");
        __builtin_amdgcn_s_barrier();   // all waves done reading sc before refill
        asm volatile("" ::: "memory");
    }

    if constexpr (BM == 128 && BN == 128) {
        // fused V transpose: write bias-added tile transposed to vt
        if (vtp != nullptr && n0 >= 1024) {
            unsigned short* sT = (unsigned short*)smem;  // [128 d][136 s]
#pragma unroll
            for (int mi = 0; mi < WM; mi++) {
                const int rl = wm * 64 + mi * 16 + quad * 4;   // s-local
#pragma unroll
                for (int nj = 0; nj < WN; nj++) {
                    const int cl = wn * 64 + nj * 16 + lm;     // d-local
                    const float bv = bias[n0 + cl];
                    ushort4 t4;
                    t4.x = f2bf(acc[mi][nj][0] + bv);
                    t4.y = f2bf(acc[mi][nj][1] + bv);
                    t4.z = f2bf(acc[mi][nj][2] + bv);
                    t4.w = f2bf(acc[mi][nj][3] + bv);
                    *(ushort4*)(sT + cl * 136 + rl) = t4;
                }
            }
            __syncthreads();
            const int b = m0 >> 8;
            const int s0 = m0 & 255;
            const int h0 = (n0 - 1024) >> 6;   // 2 heads per block
#pragma unroll
            for (int i = 0; i < 8; i++) {
                int idx = i * 256 + tid;
                int d = idx >> 4, c = idx & 15;
                uint4 v = *(const uint4*)(sT + d * 136 + c * 8);
                int bh = b * 8 + h0 + (d >> 6);
                *(uint4*)(vtp + ((size_t)bh * 64 + (d & 63)) * 256 + s0 + c * 8) = v;
            }
            return;
        }
    }

    if (gridDim.z == 1) {
        // LDS-staged coalesced C-write (row-major [BM][BN+8])
        unsigned short* sT = (unsigned short*)smem;
        constexpr int LDC = BN + 8;   // multiple of 8 -> rows 16B-aligned
#pragma unroll
        for (int mi = 0; mi < WM; mi++) {
            const int rl = wm * (WM * 16) + mi * 16 + quad * 4;
#pragma unroll
            for (int nj = 0; nj < WN; nj++) {
                const int cl = wn * (WN * 16) + nj * 16 + lm;
                const float bv = bias[n0 + cl];
#pragma unroll
                for (int r = 0; r < 4; r++) {
                    float o = acc[mi][nj][r] + bv;
                    if (act) o = fmaxf(o, 0.f);
                    sT[(rl + r) * LDC + cl] = f2bf(o);
                }
            }
        }
        __syncthreads();
        constexpr int RS = BN / 8;        // uint4 segments per row
        constexpr int TOT = BM * RS;
#pragma unroll
        for (int i = 0; i < TOT / 256; i++) {
            int idx = i * 256 + tid;
            int rr = idx / RS, cc = idx % RS;
            uint4 v = *(const uint4*)(sT + rr * LDC + cc * 8);
            *(uint4*)(Cb + (size_t)(m0 + rr) * N + n0 + cc * 8) = v;
        }
    } else {
        float* Cp = Cpart + (size_t)blockIdx.z * gridDim.y * BM * N;
#pragma unroll
        for (int mi = 0; mi < WM; mi++) {
            const int rb = m0 + wm * (WM * 16) + mi * 16 + quad * 4;
#pragma unroll
            for (int nj = 0; nj < WN; nj++) {
                const int col = n0 + wn * (WN * 16) + nj * 16 + lm;
#pragma unroll
                for (int r = 0; r < 4; r++)
                    Cp[(size_t)(rb + r) * N + col] = acc[mi][nj][r];
            }
        }
    }
}

// ---------------------------------------------------------------------------
// Fused attention (QBLK=128 form, measured 836.9/831.9): per (q-tile 128, bh).
// K staged ONCE to LDS, shared by 4 waves. S=QK^T -> no-max softmax (post-LN
// scores bounded; mask underflows to 0) -> P via LDS (wave-private rows,
// single barrier) -> O=PV -> /l -> bf16.
// [R4 lesson: QBLK=16 re-reads K/V 16x/bh = +45 us.]
// [R5 lesson: QBLK=64 doubles K-staging per computed row = +25 us. Attn is
//  staged-bandwidth-bound, not latency-bound. QBLK=128 is final.]
// ---------------------------------------------------------------------------
__global__ __launch_bounds__(256) void attn_fused(
    const unsigned short* __restrict__ qkv, const unsigned short* __restrict__ vt,
    const int* __restrict__ lens, unsigned short* __restrict__ o)
{
    __shared__ __attribute__((aligned(16))) char smem[34816];
    const int tid = threadIdx.x;
    const int wave = tid >> 6, lane = tid & 63;
    const int lm = lane & 15, quad = lane >> 4;
    const int qt = blockIdx.x;
    const int bh = blockIdx.y;
    const int b = bh >> 3, h = bh & 7;
    const int len = lens[b];
    const unsigned short* Qb = qkv + ((size_t)b * 256 + qt * 128) * 1536 + h * 64;
    const unsigned short* Kb = qkv + (size_t)b * 256 * 1536 + 512 + h * 64;
    const unsigned short* Vt = vt + (size_t)bh * 64 * 256;

#pragma unroll
    for (int j = 0; j < 8; j++) {
        int sid = wave * 8 + j;
        int nf = sid >> 1, kf = sid & 1;
        gload_lds16(Kb + (size_t)(nf * 16 + lm) * 1536 + kf * 32 + quad * 8,
                    smem + sid * 1024);
    }
    bf16x8 aq[2][2];
#pragma unroll
    for (int mi = 0; mi < 2; mi++)
#pragma unroll
        for (int kf = 0; kf < 2; kf++)
            aq[mi][kf] = *(const bf16x8*)(Qb + (size_t)(wave * 32 + mi * 16 + lm) * 1536
                                          + kf * 32 + quad * 8);
    __syncthreads();

    floatx4 accS[2][16];
#pragma unroll
    for (int mi = 0; mi < 2; mi++)
#pragma unroll
        for (int nf = 0; nf < 16; nf++) accS[mi][nf] = (floatx4){0.f, 0.f, 0.f, 0.f};

#pragma unroll
    for (int nf = 0; nf < 16; nf++) {
        bf16x8 bk0 = *(const bf16x8*)(smem + (nf * 2 + 0) * 1024 + lane * 16);
        bf16x8 bk1 = *(const bf16x8*)(smem + (nf * 2 + 1) * 1024 + lane * 16);
        accS[0][nf] = __builtin_amdgcn_mfma_f32_16x16x32_bf16(aq[0][0], bk0, accS[0][nf], 0, 0, 0);
        accS[0][nf] = __builtin_amdgcn_mfma_f32_16x16x32_bf16(aq[0][1], bk1, accS[0][nf], 0, 0, 0);
        accS[1][nf] = __builtin_amdgcn_mfma_f32_16x16x32_bf16(aq[1][0], bk0, accS[1][nf], 0, 0, 0);
        accS[1][nf] = __builtin_amdgcn_mfma_f32_16x16x32_bf16(aq[1][1], bk1, accS[1][nf], 0, 0, 0);
    }

    float lrow[2][4];
    const float scale = 0.125f;
#pragma unroll
    for (int mi = 0; mi < 2; mi++)
#pragma unroll
        for (int r = 0; r < 4; r++) {
            float sum = 0.f;
#pragma unroll
            for (int nf = 0; nf < 16; nf++) {
                float s = accS[mi][nf][r] * scale + ((nf * 16 + lm >= len) ? -1e9f : 0.f);
                float e = __expf(s);
                accS[mi][nf][r] = e;
                sum += e;
            }
#pragma unroll
            for (int off = 1; off < 16; off <<= 1) sum += __shfl_xor(sum, off, 64);
            lrow[mi][r] = sum;
        }

    floatx4 accO[2][4];
#pragma unroll
    for (int mi = 0; mi < 2; mi++)
#pragma unroll
        for (int nj = 0; nj < 4; nj++) accO[mi][nj] = (floatx4){0.f, 0.f, 0.f, 0.f};

    // single barrier: all waves done reading K-smem before P overwrites it.
    __syncthreads();
    unsigned short* sP = (unsigned short*)smem;
    const int rbase = wave * 32;
#pragma unroll
    for (int half = 0; half < 2; half++) {
#pragma unroll
        for (int mi = 0; mi < 2; mi++)
#pragma unroll
            for (int nf2 = 0; nf2 < 8; nf2++) {
                int nf = half * 8 + nf2;
                int row = rbase + mi * 16 + quad * 4;
                int col = nf2 * 16 + lm;
#pragma unroll
                for (int r = 0; r < 4; r++)
                    sP[(row + r) * 136 + col] = f2bf(accS[mi][nf][r]);
            }
#pragma unroll
        for (int ks2 = 0; ks2 < 4; ks2++) {
            bf16x8 ap[2];
#pragma unroll
            for (int mi = 0; mi < 2; mi++)
                ap[mi] = *(const bf16x8*)(sP + (rbase + mi * 16 + lm) * 136
                                          + ks2 * 32 + quad * 8);
            int ks = half * 4 + ks2;
#pragma unroll
            for (int nj = 0; nj < 4; nj++) {
                bf16x8 bv = *(const bf16x8*)(Vt + (size_t)(nj * 16 + lm) * 256
                                             + ks * 32 + quad * 8);
                accO[0][nj] = __builtin_amdgcn_mfma_f32_16x16x32_bf16(ap[0], bv, accO[0][nj], 0, 0, 0);
                accO[1][nj] = __builtin_amdgcn_mfma_f32_16x16x32_bf16(ap[1], bv, accO[1][nj], 0, 0, 0);
            }
        }
    }

#pragma unroll
    for (int mi = 0; mi < 2; mi++) {
        float inv[4];
#pragma unroll
        for (int r = 0; r < 4; r++) inv[r] = 1.f / lrow[mi][r];
        const int grow = b * 256 + qt * 128 + rbase + mi * 16 + quad * 4;
#pragma unroll
        for (int nj = 0; nj < 4; nj++) {
            const int gcol = h * 64 + nj * 16 + lm;
#pragma unroll
            for (int r = 0; r < 4; r++)
                o[(size_t)(grow + r) * 512 + gcol] = f2bf(accO[mi][nj][r] * inv[r]);
        }
    }
}

// ---------------------------------------------------------------------------
// x = LayerNorm(x + y_bf16), wave-per-row: no LDS, no barriers. 8 rows/block.
// ---------------------------------------------------------------------------
__global__ __launch_bounds__(512) void add_ln_bf16(
    unsigned short* __restrict__ x, const unsigned short* __restrict__ y,
    const float* __restrict__ s, const float* __restrict__ bb)
{
    const int wave = threadIdx.x >> 6, lane = threadIdx.x & 63;
    const int row = blockIdx.x * 8 + wave;
    const int c = lane * 8;
    u16x8 xv = *(const u16x8*)(x + (size_t)row * D_ + c);
    u16x8 yv = *(const u16x8*)(y + (size_t)row * D_ + c);
    float h[8];
    float sum = 0.f;
#pragma unroll
    for (int j = 0; j < 8; j++) {
        h[j] = bf2f(xv[j]) + bf2f(yv[j]);
        sum += h[j];
    }
#pragma unroll
    for (int off = 32; off >= 1; off >>= 1) sum += __shfl_xor(sum, off, 64);
    float mean = sum * (1.f / 512.f);

    float d[8], sq = 0.f;
#pragma unroll
    for (int j = 0; j < 8; j++) {
        d[j] = h[j] - mean;
        sq += d[j] * d[j];
    }
#pragma unroll
    for (int off = 32; off >= 1; off >>= 1) sq += __shfl_xor(sq, off, 64);
    float rs = rsqrtf(sq * (1.f / 512.f) + 1e-5f);

    float4 sv0 = *(const float4*)(s + c), sv1 = *(const float4*)(s + c + 4);
    float4 bv0 = *(const float4*)(bb + c), bv1 = *(const float4*)(bb + c + 4);
    u16x8 ov;
    ov[0] = f2bf(d[0] * rs * sv0.x + bv0.x);
    ov[1] = f2bf(d[1] * rs * sv0.y + bv0.y);
    ov[2] = f2bf(d[2] * rs * sv0.z + bv0.z);
    ov[3] = f2bf(d[3] * rs * sv0.w + bv0.w);
    ov[4] = f2bf(d[4] * rs * sv1.x + bv1.x);
    ov[5] = f2bf(d[5] * rs * sv1.y + bv1.y);
    ov[6] = f2bf(d[6] * rs * sv1.z + bv1.z);
    ov[7] = f2bf(d[7] * rs * sv1.w + bv1.w);
    *(u16x8*)(x + (size_t)row * D_ + c) = ov;
}

// ---------------------------------------------------------------------------
// x = LayerNorm(x + p0 + p1 + bias), wave-per-row; optional enc out (fp32)
// ---------------------------------------------------------------------------
__global__ __launch_bounds__(512) void add_ln_part(
    unsigned short* __restrict__ x, const float* __restrict__ p0,
    const float* __restrict__ p1, const float* __restrict__ bias,
    const float* __restrict__ s, const float* __restrict__ bb,
    float* __restrict__ enc_opt)
{
    const int wave = threadIdx.x >> 6, lane = threadIdx.x & 63;
    const int row = blockIdx.x * 8 + wave;
    const int c = lane * 8;
    u16x8 xv = *(const u16x8*)(x + (size_t)row * D_ + c);
    float4 a0 = *(const float4*)(p0 + (size_t)row * D_ + c);
    float4 a1 = *(const float4*)(p0 + (size_t)row * D_ + c + 4);
    float4 q0 = *(const float4*)(p1 + (size_t)row * D_ + c);
    float4 q1 = *(const float4*)(p1 + (size_t)row * D_ + c + 4);
    float4 bi0 = *(const float4*)(bias + c);
    float4 bi1 = *(const float4*)(bias + c + 4);
    float h[8];
    h[0] = bf2f(xv[0]) + a0.x + q0.x + bi0.x;
    h[1] = bf2f(xv[1]) + a0.y + q0.y + bi0.y;
    h[2] = bf2f(xv[2]) + a0.z + q0.z + bi0.z;
    h[3] = bf2f(xv[3]) + a0.w + q0.w + bi0.w;
    h[4] = bf2f(xv[4]) + a1.x + q1.x + bi1.x;
    h[5] = bf2f(xv[5]) + a1.y + q1.y + bi1.y;
    h[6] = bf2f(xv[6]) + a1.z + q1.z + bi1.z;
    h[7] = bf2f(xv[7]) + a1.w + q1.w + bi1.w;

    float sum = 0.f;
#pragma unroll
    for (int j = 0; j < 8; j++) sum += h[j];
#pragma unroll
    for (int off = 32; off >= 1; off >>= 1) sum += __shfl_xor(sum, off, 64);
    float mean = sum * (1.f / 512.f);

    float d[8], sq = 0.f;
#pragma unroll
    for (int j = 0; j < 8; j++) {
        d[j] = h[j] - mean;
        sq += d[j] * d[j];
    }
#pragma unroll
    for (int off = 32; off >= 1; off >>= 1) sq += __shfl_xor(sq, off, 64);
    float rs = rsqrtf(sq * (1.f / 512.f) + 1e-5f);

    float4 sv0 = *(const float4*)(s + c), sv1 = *(const float4*)(s + c + 4);
    float4 bv0 = *(const float4*)(bb + c), bv1 = *(const float4*)(bb + c + 4);
    float o[8];
    o[0] = d[0] * rs * sv0.x + bv0.x;
    o[1] = d[1] * rs * sv0.y + bv0.y;
    o[2] = d[2] * rs * sv0.z + bv0.z;
    o[3] = d[3] * rs * sv0.w + bv0.w;
    o[4] = d[4] * rs * sv1.x + bv1.x;
    o[5] = d[5] * rs * sv1.y + bv1.y;
    o[6] = d[6] * rs * sv1.z + bv1.z;
    o[7] = d[7] * rs * sv1.w + bv1.w;
    u16x8 ov;
#pragma unroll
    for (int j = 0; j < 8; j++) ov[j] = f2bf(o[j]);
    *(u16x8*)(x + (size_t)row * D_ + c) = ov;
    if (enc_opt) {
        float4 e0, e1;
        e0.x = o[0]; e0.y = o[1]; e0.z = o[2]; e0.w = o[3];
        e1.x = o[4]; e1.y = o[5]; e1.z = o[6]; e1.w = o[7];
        *(float4*)(enc_opt + (size_t)row * D_ + c) = e0;
        *(float4*)(enc_opt + (size_t)row * D_ + c + 4) = e1;
    }
}

// ---------------------------------------------------------------------------
// Head aux (merged): blocks [0,1024) = duration rows (hidden cols
// [2048,2304) of hcomb . w2 + b2 -> softplus -> round/clamp -> dint);
// blocks [1024,2304) = mel partial combine (melc = sum4(planes) + b2).
// ---------------------------------------------------------------------------
__global__ __launch_bounds__(256) void head_aux(
    const unsigned short* __restrict__ hcomb, const float* __restrict__ w2,
    const float* __restrict__ b2d, float* __restrict__ durout,
    int* __restrict__ dint,
    const float* __restrict__ mp, const float* __restrict__ b2m,
    float* __restrict__ melc)
{
    const int tid = threadIdx.x;
    int bid = blockIdx.x;
    if (bid < 1024) {
        const int w = tid >> 6, lane = tid & 63;
        const int r = bid * 4 + w;
        ushort4 hv = *(const ushort4*)(hcomb + (size_t)r * 2304 + 2048 + lane * 4);
        float4 wv = *(const float4*)(w2 + lane * 4);
        float p = bf2f(hv.x) * wv.x + bf2f(hv.y) * wv.y
                + bf2f(hv.z) * wv.z + bf2f(hv.w) * wv.w;
#pragma unroll
        for (int off = 32; off >= 1; off >>= 1) p += __shfl_xor(p, off, 64);
        if (lane == 0) {
            float v = p + b2d[0];
            float dur = (v > 20.f) ? v : log1pf(expf(v));
            durout[r] = dur;
            int d = (int)rintf(dur);
            if (d < 1) d = 1;
            dint[r] = d;
        }
        return;
    }
    bid -= 1024;
    const int idx = bid * 256 + tid;   // < 4096*80
    const int r = idx / 80, c = idx - r * 80;
    const size_t plane = (size_t)M_ * 128;
    const size_t base = (size_t)r * 128 + c;
    melc[idx] = mp[base] + mp[plane + base] + mp[2 * plane + base]
              + mp[3 * plane + base] + b2m[c];
}

// ---------------------------------------------------------------------------
// mel gather v4: per-batch cumsum computed in-block from dint, LDS-staged
// rows, coalesced writes. grid (T/256, 2 col-halves, B). melc = [4096][80].
// ---------------------------------------------------------------------------
__global__ __launch_bounds__(256) void mel_gather2(
    const float* __restrict__ melc, const float* __restrict__ c0,
    const int* __restrict__ dint, float* __restrict__ mel_out)
{
    __shared__ float rows[256 * 40];
    __shared__ int sc[256];
    __shared__ float s0[40];
    const int tid = threadIdx.x;
    const int b = blockIdx.z;
    const int cc0 = blockIdx.y * 40;
    sc[tid] = dint[b * 256 + tid];
    if (tid < 40) s0[tid] = c0[cc0 + tid];
    for (int idx = tid; idx < 256 * 40; idx += 256) {
        int r = idx / 40, c = idx - r * 40;
        rows[idx] = melc[((size_t)b * 256 + r) * 80 + cc0 + c];
    }
    __syncthreads();
    // inclusive scan of sc[0..255]
    for (int off = 1; off < 256; off <<= 1) {
        int v = sc[tid];
        int add = (tid >= off) ? sc[tid - off] : 0;
        __syncthreads();
        sc[tid] = v + add;
        __syncthreads();
    }
    const int total = sc[255];
    const int t = blockIdx.x * 256 + tid;
    int lo = 0, hi = 256;
    while (lo < hi) {
        int mid = (lo + hi) >> 1;
        if (sc[mid] <= t) lo = mid + 1; else hi = mid;
    }
    int row = lo < 255 ? lo : 255;
    const bool valid = t < total;
    const float* src = valid ? &rows[row * 40] : s0;
    for (int cc = 0; cc < 40; cc++)
        mel_out[((size_t)b * 80 + cc0 + cc) * T_ + t] = src[cc];
}

// ---------------------------------------------------------------------------
extern "C" void kernel_launch(void* const* d_in, const int* in_sizes, int n_in,
                              void* d_out, int out_size, void* d_ws, size_t ws_size,
                              hipStream_t stream)
{
    const int*   text_ids     = (const int*)d_in[0];
    const int*   text_lengths = (const int*)d_in[1];
    const float* emb   = (const float*)d_in[3];
    const float* pe    = (const float*)d_in[4];
    const float* Wqkv  = (const float*)d_in[5];
    const float* bqkv  = (const float*)d_in[6];
    const float* Wo    = (const float*)d_in[7];
    const float* bo    = (const float*)d_in[8];
    const float* ln1_s = (const float*)d_in[9];
    const float* ln1_b = (const float*)d_in[10];
    const float* ln2_s = (const float*)d_in[11];
    const float* ln2_b = (const float*)d_in[12];
    const float* W1    = (const float*)d_in[13];
    const float* b1    = (const float*)d_in[14];
    const float* W2    = (const float*)d_in[15];
    const float* b2    = (const float*)d_in[16];
    const float* mel_W1 = (const float*)d_in[17];
    const float* mel_b1 = (const float*)d_in[18];
    const float* mel_W2 = (const float*)d_in[19];
    const float* mel_b2 = (const float*)d_in[20];
    const float* dur_W1 = (const float*)d_in[21];
    const float* dur_b1 = (const float*)d_in[22];
    const float* dur_W2 = (const float*)d_in[23];
    const float* dur_b2 = (const float*)d_in[24];

    float* out = (float*)d_out;
    float* mel_out = out;
    float* dur_out = out + (size_t)B_ * NM_ * T_;
    float* enc_out = dur_out + (size_t)B_ * S_;

    typedef unsigned short u16;
    char* w = (char*)d_ws;
    u16* Wqkv_t  = (u16*)w;                   w += (size_t)L_ * 1536 * 512 * 2;
    u16* Wo_t    = (u16*)w;                   w += (size_t)L_ * 512 * 512 * 2;
    u16* W1_t    = (u16*)w;                   w += (size_t)L_ * 2048 * 512 * 2;
    u16* W2_t    = (u16*)w;                   w += (size_t)L_ * 512 * 2048 * 2;
    u16* wcomb   = (u16*)w;                   w += (size_t)2304 * 512 * 2;   // [melW1|durW1]^T
    u16* melW2_t = (u16*)w;                   w += (size_t)128 * 2048 * 2;
    u16* x_bf    = (u16*)w;                   w += (size_t)M_ * 512 * 2;
    u16* qkv_bf  = (u16*)w;                   w += (size_t)M_ * 1536 * 2;  // contiguous with
    u16* ao_bf   = (u16*)w;                   w += (size_t)M_ * 512 * 2;   // ao: 16.78MB union
    u16* y_bf    = (u16*)w;                   w += (size_t)M_ * 512 * 2;
    char* big    = w;                         w += (size_t)18874368;       // ffh/hcomb (+vt tail)
    float* c0    = (float*)w;                 w += 512;
    int*   dint  = (int*)w;                   w += (size_t)M_ * 4;
    float* cbias = (float*)w;                 w += (size_t)2304 * 4;
    float* melc  = (float*)w;                 w += (size_t)M_ * 80 * 4;

    u16* ffh     = (u16*)big;                 // [4096][2048] bf16, layer phase
    u16* hcomb   = (u16*)big;                 // [4096][2304] bf16, head phase
    u16* vt      = (u16*)(big + 12582912);    // 4MB; alive only QKV->attn

    float* part2 = (float*)qkv_bf;            // [2][4096][512] for FF2
    float* mpart = (float*)(qkv_bf + (size_t)M_ * 512);  // [4][4096][128] for mel2

    // fused weight prep (transposes + cbias + mel_c0 + embedding): 21977 blocks
    prep_weights<<<21977, 256, 0, stream>>>(
        Wqkv, Wo, W1, W2, mel_W1, mel_W2, dur_W1, mel_b1, mel_b2, dur_b1,
        text_ids, emb, pe,
        Wqkv_t, Wo_t, W1_t, W2_t, wcomb, melW2_t, cbias, c0, x_bf);

    for (int l = 0; l < L_; l++) {
        // QKV with fused V-transpose epilogue (V cols -> vt, Q/K cols -> qkv_bf)
        gemm2<128, 128><<<dim3(12, 32), 256, 0, stream>>>(
            x_bf, Wqkv_t + (size_t)l * 1536 * 512, bqkv + (size_t)l * 1536,
            qkv_bf, nullptr, vt, 1536, 512, 0, 512);
        attn_fused<<<dim3(2, 128), 256, 0, stream>>>(qkv_bf, vt, text_lengths, ao_bf);
        gemm2<128, 64><<<dim3(8, 32), 256, 0, stream>>>(
            ao_bf, Wo_t + (size_t)l * 512 * 512, bo + (size_t)l * 512,
            y_bf, nullptr, nullptr, 512, 512, 0, 512);
        add_ln_bf16<<<M_ / 8, 512, 0, stream>>>(
            x_bf, y_bf, ln1_s + (size_t)l * D_, ln1_b + (size_t)l * D_);
        gemm2<128, 128><<<dim3(16, 32), 256, 0, stream>>>(
            x_bf, W1_t + (size_t)l * 2048 * 512, b1 + (size_t)l * 2048,
            ffh, nullptr, nullptr, 2048, 512, 1, 512);
        gemm2<128, 64><<<dim3(8, 32, 2), 256, 0, stream>>>(
            ffh, W2_t + (size_t)l * 512 * 2048, nullptr,
            nullptr, part2, nullptr, 512, 1024, 0, 2048);
        add_ln_part<<<M_ / 8, 512, 0, stream>>>(
            x_bf, part2, part2 + (size_t)M_ * 512, b2 + (size_t)l * 512,
            ln2_s + (size_t)l * D_, ln2_b + (size_t)l * D_,
            (l == L_ - 1) ? enc_out : nullptr);
    }

    // merged head hidden GEMM: hcomb = relu(enc.[melW1|durW1] + [mel_b1|dur_b1])
    gemm2<128, 128><<<dim3(18, 32), 256, 0, stream>>>(
        x_bf, wcomb, cbias, hcomb, nullptr, nullptr, 2304, 512, 1, 512);

    // mel2 (split-K=4 partials), then merged dur-rows + mel-combine
    gemm2<128, 64><<<dim3(2, 32, 4), 256, 0, stream>>>(
        hcomb, melW2_t, nullptr, nullptr, mpart, nullptr, 128, 512, 0, 2304);
    head_aux<<<2304, 256, 0, stream>>>(
        hcomb, dur_W2, dur_b2, dur_out, dint, mpart, mel_b2, melc);
    // gather computes the per-batch cumsum from dint in-block
    mel_gather2<<<dim3(T_ / 256, 2, B_), 256, 0, stream>>>(melc, c0, dint, mel_out);
}